// Round 2
// baseline (574.646 us; speedup 1.0000x reference)
//
#include <hip/hip_runtime.h>
#include <hip/hip_bf16.h>

// CrossWindowAttention3D — round 5 (resubmit; prior run was an infra failure).
// Layout change: qw/kw/vw stored bf16 head-major ((widx*4+head)*216+tok)*24+d,
// aw stored fp32 in the SAME head-major window layout (contiguous per block);
// the un-shift roll moves into out_proj's gather. All epilogues restage through
// LDS and write contiguous full-line vectors.
// ws: qw|kw|vw (3 x 21.25 MB bf16) + aw (42.5 MB fp32) + B4 (0.8 MB fp32)

#define CH    96
#define DS    48
#define NVOX  (48*48*48)   // 110592
#define WSZ   6
#define NWIN  512
#define NTOK  216
#define NTOKP 224          // padded tokens (14 tiles of 16)
#define NHEADS 4
#define HD    24
#define WPAD  100
#define OPAD  100          // Outs row stride in shorts (breaks 16-way bank conflict)

typedef __attribute__((ext_vector_type(4))) float  f32x4;
typedef __attribute__((ext_vector_type(4))) short  s16x4;
typedef __attribute__((ext_vector_type(8))) short  s16x8;

static __device__ inline short f2b(float f) {
    union { float f; unsigned u; } v; v.f = f;
    unsigned r = v.u + 0x7FFF + ((v.u >> 16) & 1);   // round-to-nearest-even
    return (short)(r >> 16);
}

// ---- Kernel 1: conv1x1 + shift + window partition; bf16 head-major output ----
__global__ __launch_bounds__(256) void proj_gemm_kernel(
    const float* __restrict__ x, const float* __restrict__ W,
    const float* __restrict__ bias, const int* __restrict__ use_shift,
    short* __restrict__ dst, float scale)
{
    __shared__ float Xs[CH][64];
    __shared__ float Ws[CH][WPAD];
    __shared__ short Outs[64][OPAD];
    int tid = threadIdx.x;
    int v0 = blockIdx.x * 64;

    for (int li = tid; li < CH * CH; li += 256) {
        int oc = li / CH, k = li - oc * CH;
        Ws[oc][k] = W[li];
    }
    {
        int vl = tid & 63;
        int icg = tid >> 6;
        int v = v0 + vl;
        int d = v / (DS * DS);
        int rem = v - d * DS * DS;
        int h = rem / DS;
        int w = rem - h * DS;
        int s = (use_shift[0] != 0) ? 3 : 0;
        int sd = d + s; if (sd >= DS) sd -= DS;
        int s_h = h + s; if (s_h >= DS) s_h -= DS;
        int s_w = w + s; if (s_w >= DS) s_w -= DS;
        int src = (sd * DS + s_h) * DS + s_w;
        for (int j = 0; j < 24; j++) {
            int ic = icg * 24 + j;
            Xs[ic][vl] = x[ic * NVOX + src];
        }
    }
    __syncthreads();

    int vgrp = tid & 15;
    int ocgrp = tid >> 4;
    float acc[4][6];
#pragma unroll
    for (int i = 0; i < 4; i++)
#pragma unroll
        for (int j = 0; j < 6; j++) acc[i][j] = 0.f;

    for (int k = 0; k < CH; k += 4) {
        float4 xa = *(const float4*)&Xs[k + 0][4 * vgrp];
        float4 xb = *(const float4*)&Xs[k + 1][4 * vgrp];
        float4 xc = *(const float4*)&Xs[k + 2][4 * vgrp];
        float4 xd = *(const float4*)&Xs[k + 3][4 * vgrp];
#pragma unroll
        for (int oi = 0; oi < 6; oi++) {
            float4 wq = *(const float4*)&Ws[6 * ocgrp + oi][k];
            acc[0][oi] += xa.x * wq.x + xb.x * wq.y + xc.x * wq.z + xd.x * wq.w;
            acc[1][oi] += xa.y * wq.x + xb.y * wq.y + xc.y * wq.z + xd.y * wq.w;
            acc[2][oi] += xa.z * wq.x + xb.z * wq.y + xc.z * wq.z + xd.z * wq.w;
            acc[3][oi] += xa.w * wq.x + xb.w * wq.y + xc.w * wq.z + xd.w * wq.w;
        }
    }

    // stage bf16 result to LDS, then write contiguous 48B runs per (token, head)
#pragma unroll
    for (int vi = 0; vi < 4; vi++)
#pragma unroll
        for (int oi = 0; oi < 6; oi++)
            Outs[4 * vgrp + vi][6 * ocgrp + oi] =
                f2b((acc[vi][oi] + bias[6 * ocgrp + oi]) * scale);
    __syncthreads();

    {
        int r = tid >> 2, q = tid & 3;       // row (voxel) 0..63, head 0..3
        int v = v0 + r;
        int d = v / (DS * DS);
        int rem = v - d * DS * DS;
        int h = rem / DS;
        int w = rem - h * DS;
        int widx = (d / WSZ) * 64 + (h / WSZ) * 8 + (w / WSZ);
        int tok  = (d % WSZ) * 36 + (h % WSZ) * WSZ + (w % WSZ);
        short* dp = dst + ((size_t)(widx * NHEADS + q) * NTOK + tok) * HD;
        const short* sp = &Outs[r][q * 24];
        s16x4 a0 = *(const s16x4*)(sp);
        s16x4 a1 = *(const s16x4*)(sp + 4);
        s16x4 a2 = *(const s16x4*)(sp + 8);
        s16x4 a3 = *(const s16x4*)(sp + 12);
        s16x4 a4 = *(const s16x4*)(sp + 16);
        s16x4 a5 = *(const s16x4*)(sp + 20);
        *(s16x8*)(dp)      = __builtin_shufflevector(a0, a1, 0, 1, 2, 3, 4, 5, 6, 7);
        *(s16x8*)(dp + 8)  = __builtin_shufflevector(a2, a3, 0, 1, 2, 3, 4, 5, 6, 7);
        *(s16x8*)(dp + 16) = __builtin_shufflevector(a4, a5, 0, 1, 2, 3, 4, 5, 6, 7);
    }
}

// ---- Kernel 1b: precompute bias table B4[h][224][224] (0 in pads) ----
__global__ __launch_bounds__(256) void bias_table_kernel(
    const float* __restrict__ rel_table, float* __restrict__ B4)
{
    int idx = blockIdx.x * 256 + threadIdx.x;   // 4*224*224 = 200704, exact grid
    int h = idx / (NTOKP * NTOKP);
    int rem = idx - h * NTOKP * NTOKP;
    int i = rem / NTOKP;
    int j = rem - i * NTOKP;
    float val = 0.f;
    if (i < NTOK && j < NTOK) {
        int di = i / 36, hi = (i / 6) % 6, wi = i % 6;
        int dj = j / 36, hj = (j / 6) % 6, wj = j % 6;
        int ridx = ((di - dj + 5) * 11 + (hi - hj + 5)) * 11 + (wi - wj + 5);
        val = rel_table[ridx * NHEADS + h];
    }
    B4[idx] = val;
}

// ---- Kernel 2: MFMA windowed attention. One block per (window, head). ----
// LDS: Ks [224][36] bf16, Vt [32][248] bf16, PO = Ps/Os union (4 x 1536B),
// grp [224] int. Total 39040 B -> 4 blocks/CU.
__global__ __launch_bounds__(256, 4) void attn_mfma_kernel(
    const short* __restrict__ qw, const short* __restrict__ kw,
    const short* __restrict__ vw, const float* __restrict__ B4,
    const int* __restrict__ use_shift, float* __restrict__ aw)
{
    __shared__ short Ks[NTOKP * 36];
    __shared__ short Vt[32 * 248];
    __shared__ float PO[4][384];          // per-wave: Ps (16x36 bf16) / Os (16x24 f32)
    __shared__ int   grp_s[NTOKP];

    int widx = blockIdx.x >> 2;
    int head = blockIdx.x & 3;
    int tid = threadIdx.x;
    bool shift = (use_shift[0] != 0);
    int wd = widx >> 6, wh = (widx >> 3) & 7, ww = widx & 7;

    // zero-init staged arrays (covers pad rows/cols)
    {
        int* z2 = (int*)Ks; int* z3 = (int*)Vt;
        for (int i = tid; i < NTOKP * 18; i += 256) z2[i] = 0;
        for (int i = tid; i < 32 * 124; i += 256) z3[i] = 0;
    }
    __syncthreads();

    const size_t hbase = (size_t)(widx * NHEADS + head) * NTOK * HD;

    // fill K (row-major, stride 36) and V (transposed) via 16B vector loads
    for (int e = tid; e < NTOK * 3; e += 256) {
        int t = e / 3, ch = e - t * 3;
        const short* kp = kw + hbase + t * 24 + ch * 8;
        s16x8 k8 = *(const s16x8*)kp;
        *(s16x4*)&Ks[t * 36 + ch * 8]     = __builtin_shufflevector(k8, k8, 0, 1, 2, 3);
        *(s16x4*)&Ks[t * 36 + ch * 8 + 4] = __builtin_shufflevector(k8, k8, 4, 5, 6, 7);
        s16x8 v8 = *(const s16x8*)(vw + hbase + t * 24 + ch * 8);
#pragma unroll
        for (int j = 0; j < 8; j++) Vt[(ch * 8 + j) * 248 + t] = v8[j];
    }
    for (int t = tid; t < NTOKP; t += 256) {
        int g = 0;
        if (shift && t < NTOK) {
            int td = t / 36, th = (t / 6) % 6, tw = t % 6;
            int cd = wd * 6 + td, chh = wh * 6 + th, cw = ww * 6 + tw;
            int gd = (cd < 42) ? 0 : ((cd < 45) ? 1 : 2);
            int gh = (chh < 42) ? 0 : ((chh < 45) ? 1 : 2);
            int gw = (cw < 42) ? 0 : ((cw < 45) ? 1 : 2);
            g = gd * 9 + gh * 3 + gw;
        }
        grp_s[t] = g;
    }
    __syncthreads();

    const int wid = tid >> 6;
    const int lane = tid & 63;
    const int g = lane >> 4;     // quad 0..3
    const int c = lane & 15;     // col within tile

    const f32x4 zero4 = {0.f, 0.f, 0.f, 0.f};
    short* myPs = (short*)&PO[wid][0];
    float* myOs = &PO[wid][0];

    for (int mt = wid; mt < 14; mt += 4) {
        int m0 = mt * 16;
        // A-frag: Q rows m0+c, cols g*8..+7, straight from global (bf16, 16B)
        s16x8 aq = {0, 0, 0, 0, 0, 0, 0, 0};
        int qtok = m0 + c;
        if (g < 3 && qtok < NTOK)
            aq = *(const s16x8*)(qw + hbase + (size_t)qtok * HD + g * 8);
        // S row-strip: 14 tiles
        f32x4 sreg[14];
#pragma unroll
        for (int t = 0; t < 14; t++) {
            const short* p = &Ks[(t * 16 + c) * 36 + g * 8];
            s16x4 lo = *(const s16x4*)p;
            s16x4 hi = *(const s16x4*)(p + 4);
            s16x8 bk = __builtin_shufflevector(lo, hi, 0, 1, 2, 3, 4, 5, 6, 7);
            sreg[t] = __builtin_amdgcn_mfma_f32_16x16x32_bf16(aq, bk, zero4, 0, 0, 0);
        }
        // bias + mask + row max
        int gi[4];
        const float* brow[4];
#pragma unroll
        for (int r = 0; r < 4; r++) {
            int i = m0 + g * 4 + r;       // <= 223, in-bounds of padded tables
            gi[r] = grp_s[i];
            brow[r] = B4 + ((size_t)(head * NTOKP + i)) * NTOKP;
        }
        float mx[4] = {-1e30f, -1e30f, -1e30f, -1e30f};
#pragma unroll
        for (int t = 0; t < 14; t++) {
            int j = t * 16 + c;
            int gj = grp_s[j];
            bool padc = (j >= NTOK);
#pragma unroll
            for (int r = 0; r < 4; r++) {
                float s = sreg[t][r] + brow[r][j];
                if (gi[r] != gj) s -= 100.f;
                if (padc) s = -1e30f;
                sreg[t][r] = s;
                mx[r] = fmaxf(mx[r], s);
            }
        }
#pragma unroll
        for (int o = 1; o < 16; o <<= 1)
#pragma unroll
            for (int r = 0; r < 4; r++) mx[r] = fmaxf(mx[r], __shfl_xor(mx[r], o));
        // exp + row sum
        float sm[4] = {0.f, 0.f, 0.f, 0.f};
#pragma unroll
        for (int t = 0; t < 14; t++)
#pragma unroll
            for (int r = 0; r < 4; r++) {
                float e = __expf(sreg[t][r] - mx[r]);
                sreg[t][r] = e;
                sm[r] += e;
            }
#pragma unroll
        for (int o = 1; o < 16; o <<= 1)
#pragma unroll
            for (int r = 0; r < 4; r++) sm[r] += __shfl_xor(sm[r], o);
        float rinv[4];
#pragma unroll
        for (int r = 0; r < 4; r++) rinv[r] = 1.f / sm[r];

        // PV: 7 k-chunks of 32 tokens, P staged through per-wave LDS tile
        f32x4 o0 = zero4, o1 = zero4;
#pragma unroll 1
        for (int kt = 0; kt < 7; kt++) {
#pragma unroll
            for (int tt = 0; tt < 2; tt++) {
                int t = kt * 2 + tt;
#pragma unroll
                for (int r = 0; r < 4; r++)
                    myPs[(g * 4 + r) * 36 + tt * 16 + c] = f2b(sreg[t][r]);
            }
            const short* p = &myPs[c * 36 + g * 8];
            s16x4 lo = *(const s16x4*)p;
            s16x4 hi = *(const s16x4*)(p + 4);
            s16x8 ap = __builtin_shufflevector(lo, hi, 0, 1, 2, 3, 4, 5, 6, 7);
            const short* pv0 = &Vt[c * 248 + kt * 32 + g * 8];
            s16x4 v0l = *(const s16x4*)pv0;
            s16x4 v0h = *(const s16x4*)(pv0 + 4);
            s16x8 bv0 = __builtin_shufflevector(v0l, v0h, 0, 1, 2, 3, 4, 5, 6, 7);
            const short* pv1 = &Vt[(16 + c) * 248 + kt * 32 + g * 8];
            s16x4 v1l = *(const s16x4*)pv1;
            s16x4 v1h = *(const s16x4*)(pv1 + 4);
            s16x8 bv1 = __builtin_shufflevector(v1l, v1h, 0, 1, 2, 3, 4, 5, 6, 7);
            o0 = __builtin_amdgcn_mfma_f32_16x16x32_bf16(ap, bv0, o0, 0, 0, 0);
            o1 = __builtin_amdgcn_mfma_f32_16x16x32_bf16(ap, bv1, o1, 0, 0, 0);
        }

        // epilogue: scale by 1/sum, stage fp32 to per-wave LDS tile (reuses Ps),
        // then contiguous float4 copy-out to head-major aw
#pragma unroll
        for (int r = 0; r < 4; r++) {
            int row = g * 4 + r;
            myOs[row * 24 + c] = o0[r] * rinv[r];
            if (c < 8) myOs[row * 24 + 16 + c] = o1[r] * rinv[r];
        }
        int nrow = NTOK - m0; if (nrow > 16) nrow = 16;
        int nf = nrow * 24;                      // multiple of 4 (192 or 384)
        float* dstw = aw + hbase + (size_t)m0 * HD;
        for (int j = lane; j * 4 < nf; j += 64)
            *(float4*)(dstw + j * 4) = *(const float4*)(myOs + j * 4);
    }
}

// ---- Kernel 3: output projection; gathers head-major aw with un-shift ----
__global__ __launch_bounds__(256) void out_proj_gemm_kernel(
    const float* __restrict__ aw, const float* __restrict__ Wp,
    const float* __restrict__ bp, const int* __restrict__ use_shift,
    float* __restrict__ out)
{
    __shared__ float Xs[CH][64];
    __shared__ float Ws[CH][WPAD];
    int tid = threadIdx.x;
    int v0 = blockIdx.x * 64;

    for (int li = tid; li < CH * CH; li += 256) {
        int oc = li / CH, k = li - oc * CH;
        Ws[oc][k] = Wp[li];
    }
    {
        int vl = tid & 63;
        int hq = tid >> 6;                   // head 0..3
        int v = v0 + vl;
        int d = v / (DS * DS);
        int rem = v - d * DS * DS;
        int h = rem / DS;
        int w = rem - h * DS;
        int s = (use_shift[0] != 0) ? 3 : 0;
        int sd = d - s; if (sd < 0) sd += DS;
        int s_h = h - s; if (s_h < 0) s_h += DS;
        int s_w = w - s; if (s_w < 0) s_w += DS;
        int widx = (sd / WSZ) * 64 + (s_h / WSZ) * 8 + (s_w / WSZ);
        int tok  = (sd % WSZ) * 36 + (s_h % WSZ) * WSZ + (s_w % WSZ);
        const float* sp = aw + ((size_t)(widx * NHEADS + hq) * NTOK + tok) * HD;
#pragma unroll
        for (int j = 0; j < 6; j++) {
            float4 t4 = *(const float4*)(sp + 4 * j);
            Xs[hq * 24 + 4 * j + 0][vl] = t4.x;
            Xs[hq * 24 + 4 * j + 1][vl] = t4.y;
            Xs[hq * 24 + 4 * j + 2][vl] = t4.z;
            Xs[hq * 24 + 4 * j + 3][vl] = t4.w;
        }
    }
    __syncthreads();

    int vgrp = tid & 15;
    int ocgrp = tid >> 4;
    float acc[4][6];
#pragma unroll
    for (int i = 0; i < 4; i++)
#pragma unroll
        for (int j = 0; j < 6; j++) acc[i][j] = 0.f;

    for (int k = 0; k < CH; k += 4) {
        float4 xa = *(const float4*)&Xs[k + 0][4 * vgrp];
        float4 xb = *(const float4*)&Xs[k + 1][4 * vgrp];
        float4 xc = *(const float4*)&Xs[k + 2][4 * vgrp];
        float4 xd = *(const float4*)&Xs[k + 3][4 * vgrp];
#pragma unroll
        for (int oi = 0; oi < 6; oi++) {
            float4 wq = *(const float4*)&Ws[6 * ocgrp + oi][k];
            acc[0][oi] += xa.x * wq.x + xb.x * wq.y + xc.x * wq.z + xd.x * wq.w;
            acc[1][oi] += xa.y * wq.x + xb.y * wq.y + xc.y * wq.z + xd.y * wq.w;
            acc[2][oi] += xa.z * wq.x + xb.z * wq.y + xc.z * wq.z + xd.z * wq.w;
            acc[3][oi] += xa.w * wq.x + xb.w * wq.y + xc.w * wq.z + xd.w * wq.w;
        }
    }

#pragma unroll
    for (int oi = 0; oi < 6; oi++) {
        int oc = 6 * ocgrp + oi;
        float bb = bp[oc];
        float* op = out + (size_t)oc * NVOX + v0 + 4 * vgrp;
#pragma unroll
        for (int vi = 0; vi < 4; vi++)
            op[vi] = acc[vi][oi] + bb;
    }
}

extern "C" void kernel_launch(void* const* d_in, const int* in_sizes, int n_in,
                              void* d_out, int out_size, void* d_ws, size_t ws_size,
                              hipStream_t stream)
{
    const float* q_in = (const float*)d_in[0];
    const float* k_in = (const float*)d_in[1];
    const float* v_in = (const float*)d_in[2];
    const float* Wq   = (const float*)d_in[3];
    const float* bq   = (const float*)d_in[4];
    const float* Wk   = (const float*)d_in[5];
    const float* bk   = (const float*)d_in[6];
    const float* Wv   = (const float*)d_in[7];
    const float* bv   = (const float*)d_in[8];
    const float* Wp   = (const float*)d_in[9];
    const float* bp   = (const float*)d_in[10];
    const float* rel_table = (const float*)d_in[11];
    const int*   use_shift = (const int*)d_in[12];

    const size_t NELEM = (size_t)NWIN * NTOK * CH;   // 10,616,832
    short* qw = (short*)d_ws;                        // bf16
    short* kw = qw + NELEM;
    short* vw = kw + NELEM;
    float* aw = (float*)(vw + NELEM);                // fp32, 16B-aligned
    float* B4 = aw + NELEM;                          // 4*224*224 floats

    const float scale = 0.20412414523193154f;  // 1/sqrt(24)
    const int ggrid = NVOX / 64;               // 1728

    bias_table_kernel<<<NHEADS * NTOKP * NTOKP / 256, 256, 0, stream>>>(rel_table, B4);
    proj_gemm_kernel<<<ggrid, 256, 0, stream>>>(q_in, Wq, bq, use_shift, qw, scale);
    proj_gemm_kernel<<<ggrid, 256, 0, stream>>>(k_in, Wk, bk, use_shift, kw, 1.0f);
    proj_gemm_kernel<<<ggrid, 256, 0, stream>>>(v_in, Wv, bv, use_shift, vw, 1.0f);
    attn_mfma_kernel<<<NWIN * NHEADS, 256, 0, stream>>>(qw, kw, vw, B4, use_shift, aw);
    out_proj_gemm_kernel<<<ggrid, 256, 0, stream>>>(aw, Wp, bp, use_shift, (float*)d_out);
}

// Round 3
// 444.814 us; speedup vs baseline: 1.2919x; 1.2919x over previous
//
#include <hip/hip_runtime.h>
#include <hip/hip_bf16.h>

// CrossWindowAttention3D — round 6: fix VGPR spill (launch_bounds cap caused
// ~900MB of scratch traffic in round 5), compute rel-pos bias from a 1331-entry
// LDS table instead of the 410MB-logical B4 gather (bias index is separable:
// ridx = enc(i) - enc(j) + 665), and fuse the 3 proj launches into one.
// ws: qw|kw|vw (3 x 21.25 MB bf16) + aw (42.5 MB fp32)

#define CH    96
#define DS    48
#define NVOX  (48*48*48)   // 110592
#define WSZ   6
#define NWIN  512
#define NTOK  216
#define NTOKP 224          // padded tokens (14 tiles of 16)
#define NHEADS 4
#define HD    24
#define WPAD  100
#define OPAD  100
#define GGRID (NVOX / 64)  // 1728

typedef __attribute__((ext_vector_type(4))) float  f32x4;
typedef __attribute__((ext_vector_type(4))) short  s16x4;
typedef __attribute__((ext_vector_type(8))) short  s16x8;

static __device__ inline short f2b(float f) {
    union { float f; unsigned u; } v; v.f = f;
    unsigned r = v.u + 0x7FFF + ((v.u >> 16) & 1);   // round-to-nearest-even
    return (short)(r >> 16);
}

// ---- Kernel 1: conv1x1 + shift + window partition for q,k,v in one launch ----
// grid = 3*GGRID; blockIdx/GGRID selects which projection this block computes.
__global__ __launch_bounds__(256) void proj_gemm_kernel(
    const float* __restrict__ x0, const float* __restrict__ x1, const float* __restrict__ x2,
    const float* __restrict__ W0, const float* __restrict__ W1, const float* __restrict__ W2,
    const float* __restrict__ b0, const float* __restrict__ b1, const float* __restrict__ b2,
    const int* __restrict__ use_shift,
    short* __restrict__ d0, short* __restrict__ d1, short* __restrict__ d2,
    float scale0)
{
    __shared__ float Xs[CH][64];
    __shared__ float Ws[CH][WPAD];
    __shared__ short Outs[64][OPAD];
    int tid = threadIdx.x;
    int which = blockIdx.x / GGRID;
    int bx = blockIdx.x - which * GGRID;
    int v0 = bx * 64;

    const float* x    = (which == 0) ? x0 : ((which == 1) ? x1 : x2);
    const float* W    = (which == 0) ? W0 : ((which == 1) ? W1 : W2);
    const float* bias = (which == 0) ? b0 : ((which == 1) ? b1 : b2);
    short*       dst  = (which == 0) ? d0 : ((which == 1) ? d1 : d2);
    float scale = (which == 0) ? scale0 : 1.0f;

    for (int li = tid; li < CH * CH; li += 256) {
        int oc = li / CH, k = li - oc * CH;
        Ws[oc][k] = W[li];
    }
    {
        int vl = tid & 63;
        int icg = tid >> 6;
        int v = v0 + vl;
        int d = v / (DS * DS);
        int rem = v - d * DS * DS;
        int h = rem / DS;
        int w = rem - h * DS;
        int s = (use_shift[0] != 0) ? 3 : 0;
        int sd = d + s; if (sd >= DS) sd -= DS;
        int s_h = h + s; if (s_h >= DS) s_h -= DS;
        int s_w = w + s; if (s_w >= DS) s_w -= DS;
        int src = (sd * DS + s_h) * DS + s_w;
        for (int j = 0; j < 24; j++) {
            int ic = icg * 24 + j;
            Xs[ic][vl] = x[ic * NVOX + src];
        }
    }
    __syncthreads();

    int vgrp = tid & 15;
    int ocgrp = tid >> 4;
    float acc[4][6];
#pragma unroll
    for (int i = 0; i < 4; i++)
#pragma unroll
        for (int j = 0; j < 6; j++) acc[i][j] = 0.f;

    for (int k = 0; k < CH; k += 4) {
        float4 xa = *(const float4*)&Xs[k + 0][4 * vgrp];
        float4 xb = *(const float4*)&Xs[k + 1][4 * vgrp];
        float4 xc = *(const float4*)&Xs[k + 2][4 * vgrp];
        float4 xd = *(const float4*)&Xs[k + 3][4 * vgrp];
#pragma unroll
        for (int oi = 0; oi < 6; oi++) {
            float4 wq = *(const float4*)&Ws[6 * ocgrp + oi][k];
            acc[0][oi] += xa.x * wq.x + xb.x * wq.y + xc.x * wq.z + xd.x * wq.w;
            acc[1][oi] += xa.y * wq.x + xb.y * wq.y + xc.y * wq.z + xd.y * wq.w;
            acc[2][oi] += xa.z * wq.x + xb.z * wq.y + xc.z * wq.z + xd.z * wq.w;
            acc[3][oi] += xa.w * wq.x + xb.w * wq.y + xc.w * wq.z + xd.w * wq.w;
        }
    }

    // stage bf16 result to LDS, then write contiguous 48B runs per (token, head)
#pragma unroll
    for (int vi = 0; vi < 4; vi++)
#pragma unroll
        for (int oi = 0; oi < 6; oi++)
            Outs[4 * vgrp + vi][6 * ocgrp + oi] =
                f2b((acc[vi][oi] + bias[6 * ocgrp + oi]) * scale);
    __syncthreads();

    {
        int r = tid >> 2, q = tid & 3;       // row (voxel) 0..63, head 0..3
        int v = v0 + r;
        int d = v / (DS * DS);
        int rem = v - d * DS * DS;
        int h = rem / DS;
        int w = rem - h * DS;
        int widx = (d / WSZ) * 64 + (h / WSZ) * 8 + (w / WSZ);
        int tok  = (d % WSZ) * 36 + (h % WSZ) * WSZ + (w % WSZ);
        short* dp = dst + ((size_t)(widx * NHEADS + q) * NTOK + tok) * HD;
        const short* sp = &Outs[r][q * 24];
        s16x4 a0 = *(const s16x4*)(sp);
        s16x4 a1 = *(const s16x4*)(sp + 4);
        s16x4 a2 = *(const s16x4*)(sp + 8);
        s16x4 a3 = *(const s16x4*)(sp + 12);
        s16x4 a4 = *(const s16x4*)(sp + 16);
        s16x4 a5 = *(const s16x4*)(sp + 20);
        *(s16x8*)(dp)      = __builtin_shufflevector(a0, a1, 0, 1, 2, 3, 4, 5, 6, 7);
        *(s16x8*)(dp + 8)  = __builtin_shufflevector(a2, a3, 0, 1, 2, 3, 4, 5, 6, 7);
        *(s16x8*)(dp + 16) = __builtin_shufflevector(a4, a5, 0, 1, 2, 3, 4, 5, 6, 7);
    }
}

// ---- Kernel 2: MFMA windowed attention. One block per (window, head). ----
// LDS: Ks [224][36] bf16, Vt [32][248] bf16, PO union (4 x 1536B),
// eg_s [224] packed enc|grp, Lb [1331] per-head bias. Total 44364 B -> 3/CU.
__global__ __launch_bounds__(256) void attn_mfma_kernel(
    const short* __restrict__ qw, const short* __restrict__ kw,
    const short* __restrict__ vw, const float* __restrict__ rel_table,
    const int* __restrict__ use_shift, float* __restrict__ aw)
{
    __shared__ short Ks[NTOKP * 36];
    __shared__ short Vt[32 * 248];
    __shared__ float PO[4][384];          // per-wave: Ps (16x36 bf16) / Os (16x24 f32)
    __shared__ int   eg_s[NTOKP];         // enc(t) | (grp(t) << 16)
    __shared__ float Lb[1331];            // per-head rel-pos bias values

    int widx = blockIdx.x >> 2;
    int head = blockIdx.x & 3;
    int tid = threadIdx.x;
    bool shift = (use_shift[0] != 0);
    int wd = widx >> 6, wh = (widx >> 3) & 7, ww = widx & 7;

    // zero-init staged arrays (covers pad rows/cols)
    {
        int* z2 = (int*)Ks; int* z3 = (int*)Vt;
        for (int i = tid; i < NTOKP * 18; i += 256) z2[i] = 0;
        for (int i = tid; i < 32 * 124; i += 256) z3[i] = 0;
    }
    // per-head bias table (21 KB rel_table stays L2-resident across blocks)
    for (int i = tid; i < 1331; i += 256) Lb[i] = rel_table[i * NHEADS + head];
    __syncthreads();

    const size_t hbase = (size_t)(widx * NHEADS + head) * NTOK * HD;

    // fill K (row-major, stride 36) and V (transposed) via 16B vector loads
    for (int e = tid; e < NTOK * 3; e += 256) {
        int t = e / 3, ch = e - t * 3;
        const short* kp = kw + hbase + t * 24 + ch * 8;
        s16x8 k8 = *(const s16x8*)kp;
        *(s16x4*)&Ks[t * 36 + ch * 8]     = __builtin_shufflevector(k8, k8, 0, 1, 2, 3);
        *(s16x4*)&Ks[t * 36 + ch * 8 + 4] = __builtin_shufflevector(k8, k8, 4, 5, 6, 7);
        s16x8 v8 = *(const s16x8*)(vw + hbase + t * 24 + ch * 8);
#pragma unroll
        for (int j = 0; j < 8; j++) Vt[(ch * 8 + j) * 248 + t] = v8[j];
    }
    for (int t = tid; t < NTOKP; t += 256) {
        int e = 0, g = 0;
        if (t < NTOK) {
            int td = t / 36, th = (t / 6) % 6, tw = t % 6;
            e = td * 121 + th * 11 + tw;              // enc(t) in [0, 665]
            if (shift) {
                int cd = wd * 6 + td, chh = wh * 6 + th, cw = ww * 6 + tw;
                int gd = (cd < 42) ? 0 : ((cd < 45) ? 1 : 2);
                int gh = (chh < 42) ? 0 : ((chh < 45) ? 1 : 2);
                int gw = (cw < 42) ? 0 : ((cw < 45) ? 1 : 2);
                g = gd * 9 + gh * 3 + gw;
            }
        }
        eg_s[t] = e | (g << 16);
    }
    __syncthreads();

    const int wid = tid >> 6;
    const int lane = tid & 63;
    const int g = lane >> 4;     // quad 0..3
    const int c = lane & 15;     // col within tile

    const f32x4 zero4 = {0.f, 0.f, 0.f, 0.f};
    short* myPs = (short*)&PO[wid][0];
    float* myOs = &PO[wid][0];

    for (int mt = wid; mt < 14; mt += 4) {
        int m0 = mt * 16;
        // A-frag: Q rows m0+c, cols g*8..+7, straight from global (bf16, 16B)
        s16x8 aq = {0, 0, 0, 0, 0, 0, 0, 0};
        int qtok = m0 + c;
        if (g < 3 && qtok < NTOK)
            aq = *(const s16x8*)(qw + hbase + (size_t)qtok * HD + g * 8);
        // S row-strip: 14 tiles
        f32x4 sreg[14];
#pragma unroll
        for (int t = 0; t < 14; t++) {
            const short* p = &Ks[(t * 16 + c) * 36 + g * 8];
            s16x4 lo = *(const s16x4*)p;
            s16x4 hi = *(const s16x4*)(p + 4);
            s16x8 bk = __builtin_shufflevector(lo, hi, 0, 1, 2, 3, 4, 5, 6, 7);
            sreg[t] = __builtin_amdgcn_mfma_f32_16x16x32_bf16(aq, bk, zero4, 0, 0, 0);
        }
        // bias (from LDS, separable index) + mask + row max
        int gi[4], ei[4];
#pragma unroll
        for (int r = 0; r < 4; r++) {
            int eg = eg_s[m0 + g * 4 + r];     // row index <= 223, in-bounds
            ei[r] = eg & 0xFFFF;
            gi[r] = eg >> 16;
        }
        float mx[4] = {-1e30f, -1e30f, -1e30f, -1e30f};
#pragma unroll
        for (int t = 0; t < 14; t++) {
            int j = t * 16 + c;
            int eg = eg_s[j];
            int ej = eg & 0xFFFF, gj = eg >> 16;
            bool padc = (j >= NTOK);
#pragma unroll
            for (int r = 0; r < 4; r++) {
                float s = sreg[t][r] + Lb[ei[r] - ej + 665];
                if (gi[r] != gj) s -= 100.f;
                if (padc) s = -1e30f;
                sreg[t][r] = s;
                mx[r] = fmaxf(mx[r], s);
            }
        }
#pragma unroll
        for (int o = 1; o < 16; o <<= 1)
#pragma unroll
            for (int r = 0; r < 4; r++) mx[r] = fmaxf(mx[r], __shfl_xor(mx[r], o));
        // exp + row sum
        float sm[4] = {0.f, 0.f, 0.f, 0.f};
#pragma unroll
        for (int t = 0; t < 14; t++)
#pragma unroll
            for (int r = 0; r < 4; r++) {
                float e = __expf(sreg[t][r] - mx[r]);
                sreg[t][r] = e;
                sm[r] += e;
            }
#pragma unroll
        for (int o = 1; o < 16; o <<= 1)
#pragma unroll
            for (int r = 0; r < 4; r++) sm[r] += __shfl_xor(sm[r], o);
        float rinv[4];
#pragma unroll
        for (int r = 0; r < 4; r++) rinv[r] = 1.f / sm[r];

        // PV: 7 k-chunks of 32 tokens, P staged through per-wave LDS tile
        f32x4 o0 = zero4, o1 = zero4;
#pragma unroll 1
        for (int kt = 0; kt < 7; kt++) {
#pragma unroll
            for (int tt = 0; tt < 2; tt++) {
                int t = kt * 2 + tt;
#pragma unroll
                for (int r = 0; r < 4; r++)
                    myPs[(g * 4 + r) * 36 + tt * 16 + c] = f2b(sreg[t][r]);
            }
            const short* p = &myPs[c * 36 + g * 8];
            s16x4 lo = *(const s16x4*)p;
            s16x4 hi = *(const s16x4*)(p + 4);
            s16x8 ap = __builtin_shufflevector(lo, hi, 0, 1, 2, 3, 4, 5, 6, 7);
            const short* pv0 = &Vt[c * 248 + kt * 32 + g * 8];
            s16x4 v0l = *(const s16x4*)pv0;
            s16x4 v0h = *(const s16x4*)(pv0 + 4);
            s16x8 bv0 = __builtin_shufflevector(v0l, v0h, 0, 1, 2, 3, 4, 5, 6, 7);
            const short* pv1 = &Vt[(16 + c) * 248 + kt * 32 + g * 8];
            s16x4 v1l = *(const s16x4*)pv1;
            s16x4 v1h = *(const s16x4*)(pv1 + 4);
            s16x8 bv1 = __builtin_shufflevector(v1l, v1h, 0, 1, 2, 3, 4, 5, 6, 7);
            o0 = __builtin_amdgcn_mfma_f32_16x16x32_bf16(ap, bv0, o0, 0, 0, 0);
            o1 = __builtin_amdgcn_mfma_f32_16x16x32_bf16(ap, bv1, o1, 0, 0, 0);
        }

        // epilogue: scale by 1/sum, stage fp32 to per-wave LDS tile (reuses Ps),
        // then contiguous float4 copy-out to head-major aw
#pragma unroll
        for (int r = 0; r < 4; r++) {
            int row = g * 4 + r;
            myOs[row * 24 + c] = o0[r] * rinv[r];
            if (c < 8) myOs[row * 24 + 16 + c] = o1[r] * rinv[r];
        }
        int nrow = NTOK - m0; if (nrow > 16) nrow = 16;
        int nf = nrow * 24;                      // multiple of 4 (192 or 384)
        float* dstw = aw + hbase + (size_t)m0 * HD;
        for (int j = lane; j * 4 < nf; j += 64)
            *(float4*)(dstw + j * 4) = *(const float4*)(myOs + j * 4);
    }
}

// ---- Kernel 3: output projection; gathers head-major aw with un-shift ----
__global__ __launch_bounds__(256) void out_proj_gemm_kernel(
    const float* __restrict__ aw, const float* __restrict__ Wp,
    const float* __restrict__ bp, const int* __restrict__ use_shift,
    float* __restrict__ out)
{
    __shared__ float Xs[CH][64];
    __shared__ float Ws[CH][WPAD];
    int tid = threadIdx.x;
    int v0 = blockIdx.x * 64;

    for (int li = tid; li < CH * CH; li += 256) {
        int oc = li / CH, k = li - oc * CH;
        Ws[oc][k] = Wp[li];
    }
    {
        int vl = tid & 63;
        int hq = tid >> 6;                   // head 0..3
        int v = v0 + vl;
        int d = v / (DS * DS);
        int rem = v - d * DS * DS;
        int h = rem / DS;
        int w = rem - h * DS;
        int s = (use_shift[0] != 0) ? 3 : 0;
        int sd = d - s; if (sd < 0) sd += DS;
        int s_h = h - s; if (s_h < 0) s_h += DS;
        int s_w = w - s; if (s_w < 0) s_w += DS;
        int widx = (sd / WSZ) * 64 + (s_h / WSZ) * 8 + (s_w / WSZ);
        int tok  = (sd % WSZ) * 36 + (s_h % WSZ) * WSZ + (s_w % WSZ);
        const float* sp = aw + ((size_t)(widx * NHEADS + hq) * NTOK + tok) * HD;
#pragma unroll
        for (int j = 0; j < 6; j++) {
            float4 t4 = *(const float4*)(sp + 4 * j);
            Xs[hq * 24 + 4 * j + 0][vl] = t4.x;
            Xs[hq * 24 + 4 * j + 1][vl] = t4.y;
            Xs[hq * 24 + 4 * j + 2][vl] = t4.z;
            Xs[hq * 24 + 4 * j + 3][vl] = t4.w;
        }
    }
    __syncthreads();

    int vgrp = tid & 15;
    int ocgrp = tid >> 4;
    float acc[4][6];
#pragma unroll
    for (int i = 0; i < 4; i++)
#pragma unroll
        for (int j = 0; j < 6; j++) acc[i][j] = 0.f;

    for (int k = 0; k < CH; k += 4) {
        float4 xa = *(const float4*)&Xs[k + 0][4 * vgrp];
        float4 xb = *(const float4*)&Xs[k + 1][4 * vgrp];
        float4 xc = *(const float4*)&Xs[k + 2][4 * vgrp];
        float4 xd = *(const float4*)&Xs[k + 3][4 * vgrp];
#pragma unroll
        for (int oi = 0; oi < 6; oi++) {
            float4 wq = *(const float4*)&Ws[6 * ocgrp + oi][k];
            acc[0][oi] += xa.x * wq.x + xb.x * wq.y + xc.x * wq.z + xd.x * wq.w;
            acc[1][oi] += xa.y * wq.x + xb.y * wq.y + xc.y * wq.z + xd.y * wq.w;
            acc[2][oi] += xa.z * wq.x + xb.z * wq.y + xc.z * wq.z + xd.z * wq.w;
            acc[3][oi] += xa.w * wq.x + xb.w * wq.y + xc.w * wq.z + xd.w * wq.w;
        }
    }

#pragma unroll
    for (int oi = 0; oi < 6; oi++) {
        int oc = 6 * ocgrp + oi;
        float bb = bp[oc];
        float* op = out + (size_t)oc * NVOX + v0 + 4 * vgrp;
#pragma unroll
        for (int vi = 0; vi < 4; vi++)
            op[vi] = acc[vi][oi] + bb;
    }
}

extern "C" void kernel_launch(void* const* d_in, const int* in_sizes, int n_in,
                              void* d_out, int out_size, void* d_ws, size_t ws_size,
                              hipStream_t stream)
{
    const float* q_in = (const float*)d_in[0];
    const float* k_in = (const float*)d_in[1];
    const float* v_in = (const float*)d_in[2];
    const float* Wq   = (const float*)d_in[3];
    const float* bq   = (const float*)d_in[4];
    const float* Wk   = (const float*)d_in[5];
    const float* bk   = (const float*)d_in[6];
    const float* Wv   = (const float*)d_in[7];
    const float* bv   = (const float*)d_in[8];
    const float* Wp   = (const float*)d_in[9];
    const float* bp   = (const float*)d_in[10];
    const float* rel_table = (const float*)d_in[11];
    const int*   use_shift = (const int*)d_in[12];

    const size_t NELEM = (size_t)NWIN * NTOK * CH;   // 10,616,832
    short* qw = (short*)d_ws;                        // bf16
    short* kw = qw + NELEM;
    short* vw = kw + NELEM;
    float* aw = (float*)(vw + NELEM);                // fp32, 16B-aligned

    const float scale = 0.20412414523193154f;  // 1/sqrt(24)

    proj_gemm_kernel<<<3 * GGRID, 256, 0, stream>>>(
        q_in, k_in, v_in, Wq, Wk, Wv, bq, bk, bv, use_shift, qw, kw, vw, scale);
    attn_mfma_kernel<<<NWIN * NHEADS, 256, 0, stream>>>(qw, kw, vw, rel_table, use_shift, aw);
    out_proj_gemm_kernel<<<GGRID, 256, 0, stream>>>(aw, Wp, bp, use_shift, (float*)d_out);
}

// Round 4
// 366.806 us; speedup vs baseline: 1.5666x; 1.2127x over previous
//
#include <hip/hip_runtime.h>
#include <hip/hip_bf16.h>

// CrossWindowAttention3D — round 7: kill the scratch spill.
// Root cause found (rounds 4-6 all shared it): the PV loop was `#pragma
// unroll 1` while staging read sreg[kt*2+tt] — a RUNTIME index into a
// register array -> compiler materializes the whole 14-tile score strip in
// scratch. ~350MB/dispatch of scratch writebacks explained WRITE_SIZE=430MB.
// Fix: fully unroll PV so all sreg indices are compile-time constants.
// ws: qw|kw|vw (3 x 21.25 MB bf16) + aw (42.5 MB fp32)

#define CH    96
#define DS    48
#define NVOX  (48*48*48)   // 110592
#define WSZ   6
#define NWIN  512
#define NTOK  216
#define NTOKP 224          // padded tokens (14 tiles of 16)
#define NHEADS 4
#define HD    24
#define WPAD  100
#define OPAD  100
#define GGRID (NVOX / 64)  // 1728

typedef __attribute__((ext_vector_type(4))) float  f32x4;
typedef __attribute__((ext_vector_type(4))) short  s16x4;
typedef __attribute__((ext_vector_type(8))) short  s16x8;

static __device__ inline short f2b(float f) {
    union { float f; unsigned u; } v; v.f = f;
    unsigned r = v.u + 0x7FFF + ((v.u >> 16) & 1);   // round-to-nearest-even
    return (short)(r >> 16);
}

// ---- Kernel 1: conv1x1 + shift + window partition for q,k,v in one launch ----
// grid = 3*GGRID; blockIdx/GGRID selects which projection this block computes.
__global__ __launch_bounds__(256) void proj_gemm_kernel(
    const float* __restrict__ x0, const float* __restrict__ x1, const float* __restrict__ x2,
    const float* __restrict__ W0, const float* __restrict__ W1, const float* __restrict__ W2,
    const float* __restrict__ b0, const float* __restrict__ b1, const float* __restrict__ b2,
    const int* __restrict__ use_shift,
    short* __restrict__ d0, short* __restrict__ d1, short* __restrict__ d2,
    float scale0)
{
    __shared__ float Xs[CH][64];
    __shared__ float Ws[CH][WPAD];
    __shared__ short Outs[64][OPAD];
    int tid = threadIdx.x;
    int which = blockIdx.x / GGRID;
    int bx = blockIdx.x - which * GGRID;
    int v0 = bx * 64;

    const float* x    = (which == 0) ? x0 : ((which == 1) ? x1 : x2);
    const float* W    = (which == 0) ? W0 : ((which == 1) ? W1 : W2);
    const float* bias = (which == 0) ? b0 : ((which == 1) ? b1 : b2);
    short*       dst  = (which == 0) ? d0 : ((which == 1) ? d1 : d2);
    float scale = (which == 0) ? scale0 : 1.0f;

    for (int li = tid; li < CH * CH; li += 256) {
        int oc = li / CH, k = li - oc * CH;
        Ws[oc][k] = W[li];
    }
    {
        int vl = tid & 63;
        int icg = tid >> 6;
        int v = v0 + vl;
        int d = v / (DS * DS);
        int rem = v - d * DS * DS;
        int h = rem / DS;
        int w = rem - h * DS;
        int s = (use_shift[0] != 0) ? 3 : 0;
        int sd = d + s; if (sd >= DS) sd -= DS;
        int s_h = h + s; if (s_h >= DS) s_h -= DS;
        int s_w = w + s; if (s_w >= DS) s_w -= DS;
        int src = (sd * DS + s_h) * DS + s_w;
        for (int j = 0; j < 24; j++) {
            int ic = icg * 24 + j;
            Xs[ic][vl] = x[ic * NVOX + src];
        }
    }
    __syncthreads();

    int vgrp = tid & 15;
    int ocgrp = tid >> 4;
    float acc[4][6];
#pragma unroll
    for (int i = 0; i < 4; i++)
#pragma unroll
        for (int j = 0; j < 6; j++) acc[i][j] = 0.f;

    for (int k = 0; k < CH; k += 4) {
        float4 xa = *(const float4*)&Xs[k + 0][4 * vgrp];
        float4 xb = *(const float4*)&Xs[k + 1][4 * vgrp];
        float4 xc = *(const float4*)&Xs[k + 2][4 * vgrp];
        float4 xd = *(const float4*)&Xs[k + 3][4 * vgrp];
#pragma unroll
        for (int oi = 0; oi < 6; oi++) {
            float4 wq = *(const float4*)&Ws[6 * ocgrp + oi][k];
            acc[0][oi] += xa.x * wq.x + xb.x * wq.y + xc.x * wq.z + xd.x * wq.w;
            acc[1][oi] += xa.y * wq.x + xb.y * wq.y + xc.y * wq.z + xd.y * wq.w;
            acc[2][oi] += xa.z * wq.x + xb.z * wq.y + xc.z * wq.z + xd.z * wq.w;
            acc[3][oi] += xa.w * wq.x + xb.w * wq.y + xc.w * wq.z + xd.w * wq.w;
        }
    }

    // stage bf16 result to LDS, then write contiguous 48B runs per (token, head)
#pragma unroll
    for (int vi = 0; vi < 4; vi++)
#pragma unroll
        for (int oi = 0; oi < 6; oi++)
            Outs[4 * vgrp + vi][6 * ocgrp + oi] =
                f2b((acc[vi][oi] + bias[6 * ocgrp + oi]) * scale);
    __syncthreads();

    {
        int r = tid >> 2, q = tid & 3;       // row (voxel) 0..63, head 0..3
        int v = v0 + r;
        int d = v / (DS * DS);
        int rem = v - d * DS * DS;
        int h = rem / DS;
        int w = rem - h * DS;
        int widx = (d / WSZ) * 64 + (h / WSZ) * 8 + (w / WSZ);
        int tok  = (d % WSZ) * 36 + (h % WSZ) * WSZ + (w % WSZ);
        short* dp = dst + ((size_t)(widx * NHEADS + q) * NTOK + tok) * HD;
        const short* sp = &Outs[r][q * 24];
        s16x4 a0 = *(const s16x4*)(sp);
        s16x4 a1 = *(const s16x4*)(sp + 4);
        s16x4 a2 = *(const s16x4*)(sp + 8);
        s16x4 a3 = *(const s16x4*)(sp + 12);
        s16x4 a4 = *(const s16x4*)(sp + 16);
        s16x4 a5 = *(const s16x4*)(sp + 20);
        *(s16x8*)(dp)      = __builtin_shufflevector(a0, a1, 0, 1, 2, 3, 4, 5, 6, 7);
        *(s16x8*)(dp + 8)  = __builtin_shufflevector(a2, a3, 0, 1, 2, 3, 4, 5, 6, 7);
        *(s16x8*)(dp + 16) = __builtin_shufflevector(a4, a5, 0, 1, 2, 3, 4, 5, 6, 7);
    }
}

// ---- Kernel 2: MFMA windowed attention. One block per (window, head). ----
// LDS: Ks [224][36] bf16, Vt [32][248] bf16, PO union (4 x 1536B),
// eg_s [224] packed enc|grp, Lb [1331] per-head bias. Total 44364 B -> 3/CU.
__global__ __launch_bounds__(256) void attn_mfma_kernel(
    const short* __restrict__ qw, const short* __restrict__ kw,
    const short* __restrict__ vw, const float* __restrict__ rel_table,
    const int* __restrict__ use_shift, float* __restrict__ aw)
{
    __shared__ short Ks[NTOKP * 36];
    __shared__ short Vt[32 * 248];
    __shared__ float PO[4][384];          // per-wave: Ps (16x36 bf16) / Os (16x24 f32)
    __shared__ int   eg_s[NTOKP];         // enc(t) | (grp(t) << 16)
    __shared__ float Lb[1331];            // per-head rel-pos bias values

    int widx = blockIdx.x >> 2;
    int head = blockIdx.x & 3;
    int tid = threadIdx.x;
    bool shift = (use_shift[0] != 0);
    int wd = widx >> 6, wh = (widx >> 3) & 7, ww = widx & 7;

    // zero-init staged arrays (covers pad rows/cols)
    {
        int* z2 = (int*)Ks; int* z3 = (int*)Vt;
        for (int i = tid; i < NTOKP * 18; i += 256) z2[i] = 0;
        for (int i = tid; i < 32 * 124; i += 256) z3[i] = 0;
    }
    // per-head bias table (21 KB rel_table stays L2-resident across blocks)
    for (int i = tid; i < 1331; i += 256) Lb[i] = rel_table[i * NHEADS + head];
    __syncthreads();

    const size_t hbase = (size_t)(widx * NHEADS + head) * NTOK * HD;

    // fill K (row-major, stride 36) and V (transposed) via 16B vector loads
    for (int e = tid; e < NTOK * 3; e += 256) {
        int t = e / 3, ch = e - t * 3;
        const short* kp = kw + hbase + t * 24 + ch * 8;
        s16x8 k8 = *(const s16x8*)kp;
        *(s16x4*)&Ks[t * 36 + ch * 8]     = __builtin_shufflevector(k8, k8, 0, 1, 2, 3);
        *(s16x4*)&Ks[t * 36 + ch * 8 + 4] = __builtin_shufflevector(k8, k8, 4, 5, 6, 7);
        s16x8 v8 = *(const s16x8*)(vw + hbase + t * 24 + ch * 8);
#pragma unroll
        for (int j = 0; j < 8; j++) Vt[(ch * 8 + j) * 248 + t] = v8[j];
    }
    for (int t = tid; t < NTOKP; t += 256) {
        int e = 0, g = 0;
        if (t < NTOK) {
            int td = t / 36, th = (t / 6) % 6, tw = t % 6;
            e = td * 121 + th * 11 + tw;              // enc(t) in [0, 665]
            if (shift) {
                int cd = wd * 6 + td, chh = wh * 6 + th, cw = ww * 6 + tw;
                int gd = (cd < 42) ? 0 : ((cd < 45) ? 1 : 2);
                int gh = (chh < 42) ? 0 : ((chh < 45) ? 1 : 2);
                int gw = (cw < 42) ? 0 : ((cw < 45) ? 1 : 2);
                g = gd * 9 + gh * 3 + gw;
            }
        }
        eg_s[t] = e | (g << 16);
    }
    __syncthreads();

    const int wid = tid >> 6;
    const int lane = tid & 63;
    const int g = lane >> 4;     // quad 0..3
    const int c = lane & 15;     // col within tile

    const f32x4 zero4 = {0.f, 0.f, 0.f, 0.f};
    short* myPs = (short*)&PO[wid][0];
    float* myOs = &PO[wid][0];

    for (int mt = wid; mt < 14; mt += 4) {
        int m0 = mt * 16;
        // A-frag: Q rows m0+c, cols g*8..+7, straight from global (bf16, 16B)
        s16x8 aq = {0, 0, 0, 0, 0, 0, 0, 0};
        int qtok = m0 + c;
        if (g < 3 && qtok < NTOK)
            aq = *(const s16x8*)(qw + hbase + (size_t)qtok * HD + g * 8);
        // S row-strip: 14 tiles
        f32x4 sreg[14];
#pragma unroll
        for (int t = 0; t < 14; t++) {
            const short* p = &Ks[(t * 16 + c) * 36 + g * 8];
            s16x4 lo = *(const s16x4*)p;
            s16x4 hi = *(const s16x4*)(p + 4);
            s16x8 bk = __builtin_shufflevector(lo, hi, 0, 1, 2, 3, 4, 5, 6, 7);
            sreg[t] = __builtin_amdgcn_mfma_f32_16x16x32_bf16(aq, bk, zero4, 0, 0, 0);
        }
        // bias (from LDS, separable index) + mask + row max
        int gi[4], ei[4];
#pragma unroll
        for (int r = 0; r < 4; r++) {
            int eg = eg_s[m0 + g * 4 + r];     // row index <= 223, in-bounds
            ei[r] = eg & 0xFFFF;
            gi[r] = eg >> 16;
        }
        float mx[4] = {-1e30f, -1e30f, -1e30f, -1e30f};
#pragma unroll
        for (int t = 0; t < 14; t++) {
            int j = t * 16 + c;
            int eg = eg_s[j];
            int ej = eg & 0xFFFF, gj = eg >> 16;
            bool padc = (j >= NTOK);
#pragma unroll
            for (int r = 0; r < 4; r++) {
                float s = sreg[t][r] + Lb[ei[r] - ej + 665];
                if (gi[r] != gj) s -= 100.f;
                if (padc) s = -1e30f;
                sreg[t][r] = s;
                mx[r] = fmaxf(mx[r], s);
            }
        }
#pragma unroll
        for (int o = 1; o < 16; o <<= 1)
#pragma unroll
            for (int r = 0; r < 4; r++) mx[r] = fmaxf(mx[r], __shfl_xor(mx[r], o));
        // exp + row sum
        float sm[4] = {0.f, 0.f, 0.f, 0.f};
#pragma unroll
        for (int t = 0; t < 14; t++)
#pragma unroll
            for (int r = 0; r < 4; r++) {
                float e = __expf(sreg[t][r] - mx[r]);
                sreg[t][r] = e;
                sm[r] += e;
            }
#pragma unroll
        for (int o = 1; o < 16; o <<= 1)
#pragma unroll
            for (int r = 0; r < 4; r++) sm[r] += __shfl_xor(sm[r], o);
        float rinv[4];
#pragma unroll
        for (int r = 0; r < 4; r++) rinv[r] = 1.f / sm[r];

        // PV: 7 k-chunks of 32 tokens, P staged through per-wave LDS tile.
        // FULLY UNROLLED: every sreg index must be a compile-time constant,
        // otherwise the whole strip is forced to scratch (rule #20).
        f32x4 o0 = zero4, o1 = zero4;
#pragma unroll
        for (int kt = 0; kt < 7; kt++) {
#pragma unroll
            for (int tt = 0; tt < 2; tt++) {
                int t = kt * 2 + tt;
#pragma unroll
                for (int r = 0; r < 4; r++)
                    myPs[(g * 4 + r) * 36 + tt * 16 + c] = f2b(sreg[t][r]);
            }
            const short* p = &myPs[c * 36 + g * 8];
            s16x4 lo = *(const s16x4*)p;
            s16x4 hi = *(const s16x4*)(p + 4);
            s16x8 ap = __builtin_shufflevector(lo, hi, 0, 1, 2, 3, 4, 5, 6, 7);
            const short* pv0 = &Vt[c * 248 + kt * 32 + g * 8];
            s16x4 v0l = *(const s16x4*)pv0;
            s16x4 v0h = *(const s16x4*)(pv0 + 4);
            s16x8 bv0 = __builtin_shufflevector(v0l, v0h, 0, 1, 2, 3, 4, 5, 6, 7);
            const short* pv1 = &Vt[(16 + c) * 248 + kt * 32 + g * 8];
            s16x4 v1l = *(const s16x4*)pv1;
            s16x4 v1h = *(const s16x4*)(pv1 + 4);
            s16x8 bv1 = __builtin_shufflevector(v1l, v1h, 0, 1, 2, 3, 4, 5, 6, 7);
            o0 = __builtin_amdgcn_mfma_f32_16x16x32_bf16(ap, bv0, o0, 0, 0, 0);
            o1 = __builtin_amdgcn_mfma_f32_16x16x32_bf16(ap, bv1, o1, 0, 0, 0);
        }

        // epilogue: scale by 1/sum, stage fp32 to per-wave LDS tile (reuses Ps),
        // then contiguous float4 copy-out to head-major aw
#pragma unroll
        for (int r = 0; r < 4; r++) {
            int row = g * 4 + r;
            myOs[row * 24 + c] = o0[r] * rinv[r];
            if (c < 8) myOs[row * 24 + 16 + c] = o1[r] * rinv[r];
        }
        int nrow = NTOK - m0; if (nrow > 16) nrow = 16;
        int nf = nrow * 24;                      // multiple of 4 (192 or 384)
        float* dstw = aw + hbase + (size_t)m0 * HD;
        for (int j = lane; j * 4 < nf; j += 64)
            *(float4*)(dstw + j * 4) = *(const float4*)(myOs + j * 4);
    }
}

// ---- Kernel 3: output projection; gathers head-major aw with un-shift ----
__global__ __launch_bounds__(256) void out_proj_gemm_kernel(
    const float* __restrict__ aw, const float* __restrict__ Wp,
    const float* __restrict__ bp, const int* __restrict__ use_shift,
    float* __restrict__ out)
{
    __shared__ float Xs[CH][64];
    __shared__ float Ws[CH][WPAD];
    int tid = threadIdx.x;
    int v0 = blockIdx.x * 64;

    for (int li = tid; li < CH * CH; li += 256) {
        int oc = li / CH, k = li - oc * CH;
        Ws[oc][k] = Wp[li];
    }
    {
        int vl = tid & 63;
        int hq = tid >> 6;                   // head 0..3
        int v = v0 + vl;
        int d = v / (DS * DS);
        int rem = v - d * DS * DS;
        int h = rem / DS;
        int w = rem - h * DS;
        int s = (use_shift[0] != 0) ? 3 : 0;
        int sd = d - s; if (sd < 0) sd += DS;
        int s_h = h - s; if (s_h < 0) s_h += DS;
        int s_w = w - s; if (s_w < 0) s_w += DS;
        int widx = (sd / WSZ) * 64 + (s_h / WSZ) * 8 + (s_w / WSZ);
        int tok  = (sd % WSZ) * 36 + (s_h % WSZ) * WSZ + (s_w % WSZ);
        const float* sp = aw + ((size_t)(widx * NHEADS + hq) * NTOK + tok) * HD;
#pragma unroll
        for (int j = 0; j < 6; j++) {
            float4 t4 = *(const float4*)(sp + 4 * j);
            Xs[hq * 24 + 4 * j + 0][vl] = t4.x;
            Xs[hq * 24 + 4 * j + 1][vl] = t4.y;
            Xs[hq * 24 + 4 * j + 2][vl] = t4.z;
            Xs[hq * 24 + 4 * j + 3][vl] = t4.w;
        }
    }
    __syncthreads();

    int vgrp = tid & 15;
    int ocgrp = tid >> 4;
    float acc[4][6];
#pragma unroll
    for (int i = 0; i < 4; i++)
#pragma unroll
        for (int j = 0; j < 6; j++) acc[i][j] = 0.f;

    for (int k = 0; k < CH; k += 4) {
        float4 xa = *(const float4*)&Xs[k + 0][4 * vgrp];
        float4 xb = *(const float4*)&Xs[k + 1][4 * vgrp];
        float4 xc = *(const float4*)&Xs[k + 2][4 * vgrp];
        float4 xd = *(const float4*)&Xs[k + 3][4 * vgrp];
#pragma unroll
        for (int oi = 0; oi < 6; oi++) {
            float4 wq = *(const float4*)&Ws[6 * ocgrp + oi][k];
            acc[0][oi] += xa.x * wq.x + xb.x * wq.y + xc.x * wq.z + xd.x * wq.w;
            acc[1][oi] += xa.y * wq.x + xb.y * wq.y + xc.y * wq.z + xd.y * wq.w;
            acc[2][oi] += xa.z * wq.x + xb.z * wq.y + xc.z * wq.z + xd.z * wq.w;
            acc[3][oi] += xa.w * wq.x + xb.w * wq.y + xc.w * wq.z + xd.w * wq.w;
        }
    }

#pragma unroll
    for (int oi = 0; oi < 6; oi++) {
        int oc = 6 * ocgrp + oi;
        float bb = bp[oc];
        float* op = out + (size_t)oc * NVOX + v0 + 4 * vgrp;
#pragma unroll
        for (int vi = 0; vi < 4; vi++)
            op[vi] = acc[vi][oi] + bb;
    }
}

extern "C" void kernel_launch(void* const* d_in, const int* in_sizes, int n_in,
                              void* d_out, int out_size, void* d_ws, size_t ws_size,
                              hipStream_t stream)
{
    const float* q_in = (const float*)d_in[0];
    const float* k_in = (const float*)d_in[1];
    const float* v_in = (const float*)d_in[2];
    const float* Wq   = (const float*)d_in[3];
    const float* bq   = (const float*)d_in[4];
    const float* Wk   = (const float*)d_in[5];
    const float* bk   = (const float*)d_in[6];
    const float* Wv   = (const float*)d_in[7];
    const float* bv   = (const float*)d_in[8];
    const float* Wp   = (const float*)d_in[9];
    const float* bp   = (const float*)d_in[10];
    const float* rel_table = (const float*)d_in[11];
    const int*   use_shift = (const int*)d_in[12];

    const size_t NELEM = (size_t)NWIN * NTOK * CH;   // 10,616,832
    short* qw = (short*)d_ws;                        // bf16
    short* kw = qw + NELEM;
    short* vw = kw + NELEM;
    float* aw = (float*)(vw + NELEM);                // fp32, 16B-aligned

    const float scale = 0.20412414523193154f;  // 1/sqrt(24)

    proj_gemm_kernel<<<3 * GGRID, 256, 0, stream>>>(
        q_in, k_in, v_in, Wq, Wk, Wv, bq, bk, bv, use_shift, qw, kw, vw, scale);
    attn_mfma_kernel<<<NWIN * NHEADS, 256, 0, stream>>>(qw, kw, vw, rel_table, use_shift, aw);
    out_proj_gemm_kernel<<<GGRID, 256, 0, stream>>>(aw, Wp, bp, use_shift, (float*)d_out);
}

// Round 5
// 321.886 us; speedup vs baseline: 1.7852x; 1.1396x over previous
//
#include <hip/hip_runtime.h>
#include <hip/hip_bf16.h>

// CrossWindowAttention3D — round 8: MFMA-ize the projection GEMM.
// Round-7 counters: proj_gemm was the top kernel (150us) with IDEAL memory
// traffic (104MB fetch / 62MB write) but MfmaUtil=0, VALUBusy=61% -> pure
// VALU-bound (3.06e9 scalar FMAs ~ 39us floor). Rewrite as f16 MFMA GEMM:
// f16 inputs keep rounding error (2^-11) far below the bf16 output quantum,
// so numerics are unchanged. attn / out_proj untouched this round.
// ws: qw|kw|vw (3 x 21.25 MB bf16) + aw (42.5 MB fp32)

#define CH    96
#define DS    48
#define NVOX  (48*48*48)   // 110592
#define WSZ   6
#define NWIN  512
#define NTOK  216
#define NTOKP 224          // padded tokens (14 tiles of 16)
#define NHEADS 4
#define HD    24
#define WPAD  100
#define XSTR  100          // LDS row stride (shorts) for f16 tiles
#define PGRID (NVOX / 128) // 864 blocks per projection
#define GGRID (NVOX / 64)  // 1728 (out_proj)

typedef __attribute__((ext_vector_type(4))) float  f32x4;
typedef __attribute__((ext_vector_type(4))) short  s16x4;
typedef __attribute__((ext_vector_type(8))) short  s16x8;
typedef __attribute__((ext_vector_type(8))) _Float16 f16x8;

static __device__ inline short f2b(float f) {
    union { float f; unsigned u; } v; v.f = f;
    unsigned r = v.u + 0x7FFF + ((v.u >> 16) & 1);   // round-to-nearest-even
    return (short)(r >> 16);
}

static __device__ inline unsigned pack_f16(float a, float b) {
    unsigned short ua = __builtin_bit_cast(unsigned short, (_Float16)a);
    unsigned short ub = __builtin_bit_cast(unsigned short, (_Float16)b);
    return (unsigned)ua | ((unsigned)ub << 16);
}

// ---- Kernel 1: conv1x1 + shift + window partition via f16 MFMA ----
// grid = 3*PGRID; blockIdx/PGRID selects projection. 128 voxels per block.
// LDS: Xs[128][100] f16 (25.6KB, reused as bf16 out-stage), Wb[96][100] f16
// (19.2KB). Total 44.8KB -> 3 blocks/CU.
__global__ __launch_bounds__(256) void proj_mfma_kernel(
    const float* __restrict__ x0, const float* __restrict__ x1, const float* __restrict__ x2,
    const float* __restrict__ W0, const float* __restrict__ W1, const float* __restrict__ W2,
    const float* __restrict__ b0, const float* __restrict__ b1, const float* __restrict__ b2,
    const int* __restrict__ use_shift,
    short* __restrict__ d0, short* __restrict__ d1, short* __restrict__ d2,
    float scale0)
{
    __shared__ short Xs[128 * XSTR];   // f16 [vox][k]; later bf16 [vox][oc]
    __shared__ short Wb[CH * XSTR];    // f16 [oc][k]

    int tid = threadIdx.x;
    int which = blockIdx.x / PGRID;
    int bx = blockIdx.x - which * PGRID;
    int v0 = bx * 128;

    const float* x    = (which == 0) ? x0 : ((which == 1) ? x1 : x2);
    const float* W    = (which == 0) ? W0 : ((which == 1) ? W1 : W2);
    const float* bias = (which == 0) ? b0 : ((which == 1) ? b1 : b2);
    short*       dst  = (which == 0) ? d0 : ((which == 1) ? d1 : d2);
    float scale = (which == 0) ? scale0 : 1.0f;

    // stage W -> f16 LDS (rows = oc, k contiguous). 96*48 channel-pairs.
    for (int e = tid; e < CH * 48; e += 256) {
        int oc = e / 48, kp = e - oc * 48;
        float2 wv = *(const float2*)&W[oc * CH + 2 * kp];
        *(unsigned*)&Wb[oc * XSTR + 2 * kp] = pack_f16(wv.x, wv.y);
    }
    // stage X -> f16 LDS. Each thread owns ONE voxel, 24 channel-pairs.
    {
        int vox = tid & 127;
        int v = v0 + vox;
        int d = v / (DS * DS);
        int rem = v - d * DS * DS;
        int h = rem / DS;
        int w = rem - h * DS;
        int s = (use_shift[0] != 0) ? 3 : 0;
        int sd = d + s; if (sd >= DS) sd -= DS;
        int s_h = h + s; if (s_h >= DS) s_h -= DS;
        int s_w = w + s; if (s_w >= DS) s_w -= DS;
        int src = (sd * DS + s_h) * DS + s_w;
        for (int e = tid; e < 128 * 48; e += 256) {
            int kp = e >> 7;               // 0..47; vox = e&127 == tid&127
            float xa = x[(2 * kp) * NVOX + src];
            float xb = x[(2 * kp + 1) * NVOX + src];
            *(unsigned*)&Xs[vox * XSTR + 2 * kp] = pack_f16(xa, xb);
        }
    }
    __syncthreads();

    const int wid = tid >> 6;
    const int lane = tid & 63;
    const int g = lane >> 4;
    const int c = lane & 15;
    const int mrow = wid * 32;           // wave's 32 voxels

    const f32x4 zero4 = {0.f, 0.f, 0.f, 0.f};
    f32x4 acc[2][6];
#pragma unroll
    for (int i = 0; i < 2; i++)
#pragma unroll
        for (int j = 0; j < 6; j++) acc[i][j] = zero4;

#pragma unroll
    for (int kt = 0; kt < 3; kt++) {
        const short* pa0 = &Xs[(mrow + c) * XSTR + kt * 32 + g * 8];
        s16x4 a0l = *(const s16x4*)pa0;
        s16x4 a0h = *(const s16x4*)(pa0 + 4);
        f16x8 a0 = __builtin_bit_cast(f16x8,
            __builtin_shufflevector(a0l, a0h, 0, 1, 2, 3, 4, 5, 6, 7));
        const short* pa1 = &Xs[(mrow + 16 + c) * XSTR + kt * 32 + g * 8];
        s16x4 a1l = *(const s16x4*)pa1;
        s16x4 a1h = *(const s16x4*)(pa1 + 4);
        f16x8 a1 = __builtin_bit_cast(f16x8,
            __builtin_shufflevector(a1l, a1h, 0, 1, 2, 3, 4, 5, 6, 7));
#pragma unroll
        for (int nt = 0; nt < 6; nt++) {
            const short* pb = &Wb[(nt * 16 + c) * XSTR + kt * 32 + g * 8];
            s16x4 bl = *(const s16x4*)pb;
            s16x4 bh = *(const s16x4*)(pb + 4);
            f16x8 bb = __builtin_bit_cast(f16x8,
                __builtin_shufflevector(bl, bh, 0, 1, 2, 3, 4, 5, 6, 7));
            acc[0][nt] = __builtin_amdgcn_mfma_f32_16x16x32_f16(a0, bb, acc[0][nt], 0, 0, 0);
            acc[1][nt] = __builtin_amdgcn_mfma_f32_16x16x32_f16(a1, bb, acc[1][nt], 0, 0, 0);
        }
    }

    // per-lane bias values (oc = nt*16 + c), L2-cached scalar loads
    float bs[6];
#pragma unroll
    for (int nt = 0; nt < 6; nt++) bs[nt] = bias[nt * 16 + c];

    __syncthreads();   // all waves done reading Xs; reuse as bf16 out-stage

    // D layout: row(vox-in-tile) = g*4+r, col(oc-in-tile) = c
#pragma unroll
    for (int mtile = 0; mtile < 2; mtile++)
#pragma unroll
        for (int nt = 0; nt < 6; nt++)
#pragma unroll
            for (int r = 0; r < 4; r++) {
                int vox = mrow + mtile * 16 + g * 4 + r;
                int oc = nt * 16 + c;
                Xs[vox * XSTR + oc] = f2b((acc[mtile][nt][r] + bs[nt]) * scale);
            }
    __syncthreads();

    // copy-out: 128 vox x 4 heads, contiguous 48B run per (token, head)
    for (int e = tid; e < 512; e += 256) {
        int vox = e >> 2, q = e & 3;
        int v = v0 + vox;
        int d = v / (DS * DS);
        int rem = v - d * DS * DS;
        int h = rem / DS;
        int w = rem - h * DS;
        int widx = (d / WSZ) * 64 + (h / WSZ) * 8 + (w / WSZ);
        int tok  = (d % WSZ) * 36 + (h % WSZ) * WSZ + (w % WSZ);
        short* dp = dst + ((size_t)(widx * NHEADS + q) * NTOK + tok) * HD;
        const short* sp = &Xs[vox * XSTR + q * 24];
        s16x4 a0 = *(const s16x4*)(sp);
        s16x4 a1 = *(const s16x4*)(sp + 4);
        s16x4 a2 = *(const s16x4*)(sp + 8);
        s16x4 a3 = *(const s16x4*)(sp + 12);
        s16x4 a4 = *(const s16x4*)(sp + 16);
        s16x4 a5 = *(const s16x4*)(sp + 20);
        *(s16x8*)(dp)      = __builtin_shufflevector(a0, a1, 0, 1, 2, 3, 4, 5, 6, 7);
        *(s16x8*)(dp + 8)  = __builtin_shufflevector(a2, a3, 0, 1, 2, 3, 4, 5, 6, 7);
        *(s16x8*)(dp + 16) = __builtin_shufflevector(a4, a5, 0, 1, 2, 3, 4, 5, 6, 7);
    }
}

// ---- Kernel 2: MFMA windowed attention (unchanged from round 7) ----
__global__ __launch_bounds__(256) void attn_mfma_kernel(
    const short* __restrict__ qw, const short* __restrict__ kw,
    const short* __restrict__ vw, const float* __restrict__ rel_table,
    const int* __restrict__ use_shift, float* __restrict__ aw)
{
    __shared__ short Ks[NTOKP * 36];
    __shared__ short Vt[32 * 248];
    __shared__ float PO[4][384];          // per-wave: Ps (16x36 bf16) / Os (16x24 f32)
    __shared__ int   eg_s[NTOKP];         // enc(t) | (grp(t) << 16)
    __shared__ float Lb[1331];            // per-head rel-pos bias values

    int widx = blockIdx.x >> 2;
    int head = blockIdx.x & 3;
    int tid = threadIdx.x;
    bool shift = (use_shift[0] != 0);
    int wd = widx >> 6, wh = (widx >> 3) & 7, ww = widx & 7;

    {
        int* z2 = (int*)Ks; int* z3 = (int*)Vt;
        for (int i = tid; i < NTOKP * 18; i += 256) z2[i] = 0;
        for (int i = tid; i < 32 * 124; i += 256) z3[i] = 0;
    }
    for (int i = tid; i < 1331; i += 256) Lb[i] = rel_table[i * NHEADS + head];
    __syncthreads();

    const size_t hbase = (size_t)(widx * NHEADS + head) * NTOK * HD;

    for (int e = tid; e < NTOK * 3; e += 256) {
        int t = e / 3, ch = e - t * 3;
        const short* kp = kw + hbase + t * 24 + ch * 8;
        s16x8 k8 = *(const s16x8*)kp;
        *(s16x4*)&Ks[t * 36 + ch * 8]     = __builtin_shufflevector(k8, k8, 0, 1, 2, 3);
        *(s16x4*)&Ks[t * 36 + ch * 8 + 4] = __builtin_shufflevector(k8, k8, 4, 5, 6, 7);
        s16x8 v8 = *(const s16x8*)(vw + hbase + t * 24 + ch * 8);
#pragma unroll
        for (int j = 0; j < 8; j++) Vt[(ch * 8 + j) * 248 + t] = v8[j];
    }
    for (int t = tid; t < NTOKP; t += 256) {
        int e = 0, g = 0;
        if (t < NTOK) {
            int td = t / 36, th = (t / 6) % 6, tw = t % 6;
            e = td * 121 + th * 11 + tw;              // enc(t) in [0, 665]
            if (shift) {
                int cd = wd * 6 + td, chh = wh * 6 + th, cw = ww * 6 + tw;
                int gd = (cd < 42) ? 0 : ((cd < 45) ? 1 : 2);
                int gh = (chh < 42) ? 0 : ((chh < 45) ? 1 : 2);
                int gw = (cw < 42) ? 0 : ((cw < 45) ? 1 : 2);
                g = gd * 9 + gh * 3 + gw;
            }
        }
        eg_s[t] = e | (g << 16);
    }
    __syncthreads();

    const int wid = tid >> 6;
    const int lane = tid & 63;
    const int g = lane >> 4;     // quad 0..3
    const int c = lane & 15;     // col within tile

    const f32x4 zero4 = {0.f, 0.f, 0.f, 0.f};
    short* myPs = (short*)&PO[wid][0];
    float* myOs = &PO[wid][0];

    for (int mt = wid; mt < 14; mt += 4) {
        int m0 = mt * 16;
        s16x8 aq = {0, 0, 0, 0, 0, 0, 0, 0};
        int qtok = m0 + c;
        if (g < 3 && qtok < NTOK)
            aq = *(const s16x8*)(qw + hbase + (size_t)qtok * HD + g * 8);
        f32x4 sreg[14];
#pragma unroll
        for (int t = 0; t < 14; t++) {
            const short* p = &Ks[(t * 16 + c) * 36 + g * 8];
            s16x4 lo = *(const s16x4*)p;
            s16x4 hi = *(const s16x4*)(p + 4);
            s16x8 bk = __builtin_shufflevector(lo, hi, 0, 1, 2, 3, 4, 5, 6, 7);
            sreg[t] = __builtin_amdgcn_mfma_f32_16x16x32_bf16(aq, bk, zero4, 0, 0, 0);
        }
        int gi[4], ei[4];
#pragma unroll
        for (int r = 0; r < 4; r++) {
            int eg = eg_s[m0 + g * 4 + r];
            ei[r] = eg & 0xFFFF;
            gi[r] = eg >> 16;
        }
        float mx[4] = {-1e30f, -1e30f, -1e30f, -1e30f};
#pragma unroll
        for (int t = 0; t < 14; t++) {
            int j = t * 16 + c;
            int eg = eg_s[j];
            int ej = eg & 0xFFFF, gj = eg >> 16;
            bool padc = (j >= NTOK);
#pragma unroll
            for (int r = 0; r < 4; r++) {
                float s = sreg[t][r] + Lb[ei[r] - ej + 665];
                if (gi[r] != gj) s -= 100.f;
                if (padc) s = -1e30f;
                sreg[t][r] = s;
                mx[r] = fmaxf(mx[r], s);
            }
        }
#pragma unroll
        for (int o = 1; o < 16; o <<= 1)
#pragma unroll
            for (int r = 0; r < 4; r++) mx[r] = fmaxf(mx[r], __shfl_xor(mx[r], o));
        float sm[4] = {0.f, 0.f, 0.f, 0.f};
#pragma unroll
        for (int t = 0; t < 14; t++)
#pragma unroll
            for (int r = 0; r < 4; r++) {
                float e = __expf(sreg[t][r] - mx[r]);
                sreg[t][r] = e;
                sm[r] += e;
            }
#pragma unroll
        for (int o = 1; o < 16; o <<= 1)
#pragma unroll
            for (int r = 0; r < 4; r++) sm[r] += __shfl_xor(sm[r], o);
        float rinv[4];
#pragma unroll
        for (int r = 0; r < 4; r++) rinv[r] = 1.f / sm[r];

        // PV fully unrolled (all sreg indices compile-time constants)
        f32x4 o0 = zero4, o1 = zero4;
#pragma unroll
        for (int kt = 0; kt < 7; kt++) {
#pragma unroll
            for (int tt = 0; tt < 2; tt++) {
                int t = kt * 2 + tt;
#pragma unroll
                for (int r = 0; r < 4; r++)
                    myPs[(g * 4 + r) * 36 + tt * 16 + c] = f2b(sreg[t][r]);
            }
            const short* p = &myPs[c * 36 + g * 8];
            s16x4 lo = *(const s16x4*)p;
            s16x4 hi = *(const s16x4*)(p + 4);
            s16x8 ap = __builtin_shufflevector(lo, hi, 0, 1, 2, 3, 4, 5, 6, 7);
            const short* pv0 = &Vt[c * 248 + kt * 32 + g * 8];
            s16x4 v0l = *(const s16x4*)pv0;
            s16x4 v0h = *(const s16x4*)(pv0 + 4);
            s16x8 bv0 = __builtin_shufflevector(v0l, v0h, 0, 1, 2, 3, 4, 5, 6, 7);
            const short* pv1 = &Vt[(16 + c) * 248 + kt * 32 + g * 8];
            s16x4 v1l = *(const s16x4*)pv1;
            s16x4 v1h = *(const s16x4*)(pv1 + 4);
            s16x8 bv1 = __builtin_shufflevector(v1l, v1h, 0, 1, 2, 3, 4, 5, 6, 7);
            o0 = __builtin_amdgcn_mfma_f32_16x16x32_bf16(ap, bv0, o0, 0, 0, 0);
            o1 = __builtin_amdgcn_mfma_f32_16x16x32_bf16(ap, bv1, o1, 0, 0, 0);
        }

#pragma unroll
        for (int r = 0; r < 4; r++) {
            int row = g * 4 + r;
            myOs[row * 24 + c] = o0[r] * rinv[r];
            if (c < 8) myOs[row * 24 + 16 + c] = o1[r] * rinv[r];
        }
        int nrow = NTOK - m0; if (nrow > 16) nrow = 16;
        int nf = nrow * 24;
        float* dstw = aw + hbase + (size_t)m0 * HD;
        for (int j = lane; j * 4 < nf; j += 64)
            *(float4*)(dstw + j * 4) = *(const float4*)(myOs + j * 4);
    }
}

// ---- Kernel 3: output projection (unchanged from round 7) ----
__global__ __launch_bounds__(256) void out_proj_gemm_kernel(
    const float* __restrict__ aw, const float* __restrict__ Wp,
    const float* __restrict__ bp, const int* __restrict__ use_shift,
    float* __restrict__ out)
{
    __shared__ float Xs[CH][64];
    __shared__ float Ws[CH][WPAD];
    int tid = threadIdx.x;
    int v0 = blockIdx.x * 64;

    for (int li = tid; li < CH * CH; li += 256) {
        int oc = li / CH, k = li - oc * CH;
        Ws[oc][k] = Wp[li];
    }
    {
        int vl = tid & 63;
        int hq = tid >> 6;                   // head 0..3
        int v = v0 + vl;
        int d = v / (DS * DS);
        int rem = v - d * DS * DS;
        int h = rem / DS;
        int w = rem - h * DS;
        int s = (use_shift[0] != 0) ? 3 : 0;
        int sd = d - s; if (sd < 0) sd += DS;
        int s_h = h - s; if (s_h < 0) s_h += DS;
        int s_w = w - s; if (s_w < 0) s_w += DS;
        int widx = (sd / WSZ) * 64 + (s_h / WSZ) * 8 + (s_w / WSZ);
        int tok  = (sd % WSZ) * 36 + (s_h % WSZ) * WSZ + (s_w % WSZ);
        const float* sp = aw + ((size_t)(widx * NHEADS + hq) * NTOK + tok) * HD;
#pragma unroll
        for (int j = 0; j < 6; j++) {
            float4 t4 = *(const float4*)(sp + 4 * j);
            Xs[hq * 24 + 4 * j + 0][vl] = t4.x;
            Xs[hq * 24 + 4 * j + 1][vl] = t4.y;
            Xs[hq * 24 + 4 * j + 2][vl] = t4.z;
            Xs[hq * 24 + 4 * j + 3][vl] = t4.w;
        }
    }
    __syncthreads();

    int vgrp = tid & 15;
    int ocgrp = tid >> 4;
    float acc[4][6];
#pragma unroll
    for (int i = 0; i < 4; i++)
#pragma unroll
        for (int j = 0; j < 6; j++) acc[i][j] = 0.f;

    for (int k = 0; k < CH; k += 4) {
        float4 xa = *(const float4*)&Xs[k + 0][4 * vgrp];
        float4 xb = *(const float4*)&Xs[k + 1][4 * vgrp];
        float4 xc = *(const float4*)&Xs[k + 2][4 * vgrp];
        float4 xd = *(const float4*)&Xs[k + 3][4 * vgrp];
#pragma unroll
        for (int oi = 0; oi < 6; oi++) {
            float4 wq = *(const float4*)&Ws[6 * ocgrp + oi][k];
            acc[0][oi] += xa.x * wq.x + xb.x * wq.y + xc.x * wq.z + xd.x * wq.w;
            acc[1][oi] += xa.y * wq.x + xb.y * wq.y + xc.y * wq.z + xd.y * wq.w;
            acc[2][oi] += xa.z * wq.x + xb.z * wq.y + xc.z * wq.z + xd.z * wq.w;
            acc[3][oi] += xa.w * wq.x + xb.w * wq.y + xc.w * wq.z + xd.w * wq.w;
        }
    }

#pragma unroll
    for (int oi = 0; oi < 6; oi++) {
        int oc = 6 * ocgrp + oi;
        float bb = bp[oc];
        float* op = out + (size_t)oc * NVOX + v0 + 4 * vgrp;
#pragma unroll
        for (int vi = 0; vi < 4; vi++)
            op[vi] = acc[vi][oi] + bb;
    }
}

extern "C" void kernel_launch(void* const* d_in, const int* in_sizes, int n_in,
                              void* d_out, int out_size, void* d_ws, size_t ws_size,
                              hipStream_t stream)
{
    const float* q_in = (const float*)d_in[0];
    const float* k_in = (const float*)d_in[1];
    const float* v_in = (const float*)d_in[2];
    const float* Wq   = (const float*)d_in[3];
    const float* bq   = (const float*)d_in[4];
    const float* Wk   = (const float*)d_in[5];
    const float* bk   = (const float*)d_in[6];
    const float* Wv   = (const float*)d_in[7];
    const float* bv   = (const float*)d_in[8];
    const float* Wp   = (const float*)d_in[9];
    const float* bp   = (const float*)d_in[10];
    const float* rel_table = (const float*)d_in[11];
    const int*   use_shift = (const int*)d_in[12];

    const size_t NELEM = (size_t)NWIN * NTOK * CH;   // 10,616,832
    short* qw = (short*)d_ws;                        // bf16
    short* kw = qw + NELEM;
    short* vw = kw + NELEM;
    float* aw = (float*)(vw + NELEM);                // fp32, 16B-aligned

    const float scale = 0.20412414523193154f;  // 1/sqrt(24)

    proj_mfma_kernel<<<3 * PGRID, 256, 0, stream>>>(
        q_in, k_in, v_in, Wq, Wk, Wv, bq, bk, bv, use_shift, qw, kw, vw, scale);
    attn_mfma_kernel<<<NWIN * NHEADS, 256, 0, stream>>>(qw, kw, vw, rel_table, use_shift, aw);
    out_proj_gemm_kernel<<<GGRID, 256, 0, stream>>>(aw, Wp, bp, use_shift, (float*)d_out);
}

// Round 6
// 304.207 us; speedup vs baseline: 1.8890x; 1.0581x over previous
//
#include <hip/hip_runtime.h>
#include <hip/hip_bf16.h>

// CrossWindowAttention3D — round 9.
// attn (87us, VALUBusy 58%, Occ 26%): (1) fixed-shift softmax (exp(s-8), no
// row-max pass/reduce — shift-invariance), (2) LDS 44.5K->40.5K => 4 blocks/CU,
// (3) aw stored bf16. out_proj rewritten as f16 MFMA with swapped operands
// (D[oc][vox]) for coalesced direct stores. proj unchanged from round 8.
// ws: qw|kw|vw|aw (4 x 21.25 MB bf16)

#define CH    96
#define DS    48
#define NVOX  (48*48*48)   // 110592
#define WSZ   6
#define NWIN  512
#define NTOK  216
#define NTOKP 224
#define NHEADS 4
#define HD    24
#define XSTR  100          // LDS row stride (shorts) for f16 GEMM tiles
#define VSTR  228          // Vt row stride (shorts)
#define PGRID (NVOX / 128) // 864 blocks per projection
#define CEXP  8.0f

typedef __attribute__((ext_vector_type(4))) float  f32x4;
typedef __attribute__((ext_vector_type(4))) short  s16x4;
typedef __attribute__((ext_vector_type(8))) short  s16x8;
typedef __attribute__((ext_vector_type(8))) _Float16 f16x8;

static __device__ inline short f2b(float f) {
    union { float f; unsigned u; } v; v.f = f;
    unsigned r = v.u + 0x7FFF + ((v.u >> 16) & 1);   // RTNE
    return (short)(r >> 16);
}
static __device__ inline float bf2f(short s) {
    union { unsigned u; float f; } v;
    v.u = ((unsigned)(unsigned short)s) << 16;
    return v.f;
}
static __device__ inline unsigned pack_f16(float a, float b) {
    unsigned short ua = __builtin_bit_cast(unsigned short, (_Float16)a);
    unsigned short ub = __builtin_bit_cast(unsigned short, (_Float16)b);
    return (unsigned)ua | ((unsigned)ub << 16);
}

// ---- Kernel 1: conv1x1 + shift + window partition via f16 MFMA (round 8) ----
__global__ __launch_bounds__(256) void proj_mfma_kernel(
    const float* __restrict__ x0, const float* __restrict__ x1, const float* __restrict__ x2,
    const float* __restrict__ W0, const float* __restrict__ W1, const float* __restrict__ W2,
    const float* __restrict__ b0, const float* __restrict__ b1, const float* __restrict__ b2,
    const int* __restrict__ use_shift,
    short* __restrict__ d0, short* __restrict__ d1, short* __restrict__ d2,
    float scale0)
{
    __shared__ short Xs[128 * XSTR];   // f16 [vox][k]; later bf16 [vox][oc]
    __shared__ short Wb[CH * XSTR];    // f16 [oc][k]

    int tid = threadIdx.x;
    int which = blockIdx.x / PGRID;
    int bx = blockIdx.x - which * PGRID;
    int v0 = bx * 128;

    const float* x    = (which == 0) ? x0 : ((which == 1) ? x1 : x2);
    const float* W    = (which == 0) ? W0 : ((which == 1) ? W1 : W2);
    const float* bias = (which == 0) ? b0 : ((which == 1) ? b1 : b2);
    short*       dst  = (which == 0) ? d0 : ((which == 1) ? d1 : d2);
    float scale = (which == 0) ? scale0 : 1.0f;

    for (int e = tid; e < CH * 48; e += 256) {
        int oc = e / 48, kp = e - oc * 48;
        float2 wv = *(const float2*)&W[oc * CH + 2 * kp];
        *(unsigned*)&Wb[oc * XSTR + 2 * kp] = pack_f16(wv.x, wv.y);
    }
    {
        int vox = tid & 127;
        int v = v0 + vox;
        int d = v / (DS * DS);
        int rem = v - d * DS * DS;
        int h = rem / DS;
        int w = rem - h * DS;
        int s = (use_shift[0] != 0) ? 3 : 0;
        int sd = d + s; if (sd >= DS) sd -= DS;
        int s_h = h + s; if (s_h >= DS) s_h -= DS;
        int s_w = w + s; if (s_w >= DS) s_w -= DS;
        int src = (sd * DS + s_h) * DS + s_w;
        for (int e = tid; e < 128 * 48; e += 256) {
            int kp = e >> 7;
            float xa = x[(2 * kp) * NVOX + src];
            float xb = x[(2 * kp + 1) * NVOX + src];
            *(unsigned*)&Xs[vox * XSTR + 2 * kp] = pack_f16(xa, xb);
        }
    }
    __syncthreads();

    const int wid = tid >> 6;
    const int lane = tid & 63;
    const int g = lane >> 4;
    const int c = lane & 15;
    const int mrow = wid * 32;

    const f32x4 zero4 = {0.f, 0.f, 0.f, 0.f};
    f32x4 acc[2][6];
#pragma unroll
    for (int i = 0; i < 2; i++)
#pragma unroll
        for (int j = 0; j < 6; j++) acc[i][j] = zero4;

#pragma unroll
    for (int kt = 0; kt < 3; kt++) {
        const short* pa0 = &Xs[(mrow + c) * XSTR + kt * 32 + g * 8];
        s16x4 a0l = *(const s16x4*)pa0;
        s16x4 a0h = *(const s16x4*)(pa0 + 4);
        f16x8 a0 = __builtin_bit_cast(f16x8,
            __builtin_shufflevector(a0l, a0h, 0, 1, 2, 3, 4, 5, 6, 7));
        const short* pa1 = &Xs[(mrow + 16 + c) * XSTR + kt * 32 + g * 8];
        s16x4 a1l = *(const s16x4*)pa1;
        s16x4 a1h = *(const s16x4*)(pa1 + 4);
        f16x8 a1 = __builtin_bit_cast(f16x8,
            __builtin_shufflevector(a1l, a1h, 0, 1, 2, 3, 4, 5, 6, 7));
#pragma unroll
        for (int nt = 0; nt < 6; nt++) {
            const short* pb = &Wb[(nt * 16 + c) * XSTR + kt * 32 + g * 8];
            s16x4 bl = *(const s16x4*)pb;
            s16x4 bh = *(const s16x4*)(pb + 4);
            f16x8 bb = __builtin_bit_cast(f16x8,
                __builtin_shufflevector(bl, bh, 0, 1, 2, 3, 4, 5, 6, 7));
            acc[0][nt] = __builtin_amdgcn_mfma_f32_16x16x32_f16(a0, bb, acc[0][nt], 0, 0, 0);
            acc[1][nt] = __builtin_amdgcn_mfma_f32_16x16x32_f16(a1, bb, acc[1][nt], 0, 0, 0);
        }
    }

    float bs[6];
#pragma unroll
    for (int nt = 0; nt < 6; nt++) bs[nt] = bias[nt * 16 + c];

    __syncthreads();

#pragma unroll
    for (int mtile = 0; mtile < 2; mtile++)
#pragma unroll
        for (int nt = 0; nt < 6; nt++)
#pragma unroll
            for (int r = 0; r < 4; r++) {
                int vox = mrow + mtile * 16 + g * 4 + r;
                int oc = nt * 16 + c;
                Xs[vox * XSTR + oc] = f2b((acc[mtile][nt][r] + bs[nt]) * scale);
            }
    __syncthreads();

    for (int e = tid; e < 512; e += 256) {
        int vox = e >> 2, q = e & 3;
        int v = v0 + vox;
        int d = v / (DS * DS);
        int rem = v - d * DS * DS;
        int h = rem / DS;
        int w = rem - h * DS;
        int widx = (d / WSZ) * 64 + (h / WSZ) * 8 + (w / WSZ);
        int tok  = (d % WSZ) * 36 + (h % WSZ) * WSZ + (w % WSZ);
        short* dp = dst + ((size_t)(widx * NHEADS + q) * NTOK + tok) * HD;
        const short* sp = &Xs[vox * XSTR + q * 24];
        s16x4 a0 = *(const s16x4*)(sp);
        s16x4 a1 = *(const s16x4*)(sp + 4);
        s16x4 a2 = *(const s16x4*)(sp + 8);
        s16x4 a3 = *(const s16x4*)(sp + 12);
        s16x4 a4 = *(const s16x4*)(sp + 16);
        s16x4 a5 = *(const s16x4*)(sp + 20);
        *(s16x8*)(dp)      = __builtin_shufflevector(a0, a1, 0, 1, 2, 3, 4, 5, 6, 7);
        *(s16x8*)(dp + 8)  = __builtin_shufflevector(a2, a3, 0, 1, 2, 3, 4, 5, 6, 7);
        *(s16x8*)(dp + 16) = __builtin_shufflevector(a4, a5, 0, 1, 2, 3, 4, 5, 6, 7);
    }
}

// ---- Kernel 2: MFMA windowed attention. One block per (window, head). ----
// LDS: Ks[216*36] 15552 + Vt[32*228] 14592 + PO 4608 + eg 448 + Lb 5324
// = 40524 B -> 4 blocks/CU.
__global__ __launch_bounds__(256) void attn_mfma_kernel(
    const short* __restrict__ qw, const short* __restrict__ kw,
    const short* __restrict__ vw, const float* __restrict__ rel_table,
    const int* __restrict__ use_shift, short* __restrict__ aw)
{
    __shared__ short Ks[NTOK * 36];
    __shared__ short Vt[32 * VSTR];
    __shared__ short PO[4][576];          // per-wave: Ps bf16[16][36] / Os bf16[16][24]
    __shared__ short eg_s[NTOKP];         // enc(t) | grp(t)<<10
    __shared__ float Lb[1331];            // per-head rel-pos bias

    int widx = blockIdx.x >> 2;
    int head = blockIdx.x & 3;
    int tid = threadIdx.x;
    bool shift = (use_shift[0] != 0);
    int wd = widx >> 6, wh = (widx >> 3) & 7, ww = widx & 7;

    {
        int* z2 = (int*)Ks; int* z3 = (int*)Vt;
        for (int i = tid; i < NTOK * 18; i += 256) z2[i] = 0;
        for (int i = tid; i < 16 * VSTR; i += 256) z3[i] = 0;
    }
    for (int i = tid; i < 1331; i += 256) Lb[i] = rel_table[i * NHEADS + head];
    __syncthreads();

    const size_t hbase = (size_t)(widx * NHEADS + head) * NTOK * HD;

    for (int e = tid; e < NTOK * 3; e += 256) {
        int t = e / 3, ch = e - t * 3;
        const short* kp = kw + hbase + t * 24 + ch * 8;
        s16x8 k8 = *(const s16x8*)kp;
        *(s16x4*)&Ks[t * 36 + ch * 8]     = __builtin_shufflevector(k8, k8, 0, 1, 2, 3);
        *(s16x4*)&Ks[t * 36 + ch * 8 + 4] = __builtin_shufflevector(k8, k8, 4, 5, 6, 7);
        s16x8 v8 = *(const s16x8*)(vw + hbase + t * 24 + ch * 8);
#pragma unroll
        for (int j = 0; j < 8; j++) Vt[(ch * 8 + j) * VSTR + t] = v8[j];
    }
    for (int t = tid; t < NTOKP; t += 256) {
        int e = 0, g = 0;
        if (t < NTOK) {
            int td = t / 36, th = (t / 6) % 6, tw = t % 6;
            e = td * 121 + th * 11 + tw;              // enc(t) in [0, 665]
            if (shift) {
                int cd = wd * 6 + td, chh = wh * 6 + th, cw = ww * 6 + tw;
                int gd = (cd < 42) ? 0 : ((cd < 45) ? 1 : 2);
                int gh = (chh < 42) ? 0 : ((chh < 45) ? 1 : 2);
                int gw = (cw < 42) ? 0 : ((cw < 45) ? 1 : 2);
                g = gd * 9 + gh * 3 + gw;
            }
        }
        eg_s[t] = (short)(e | (g << 10));
    }
    __syncthreads();

    const int wid = tid >> 6;
    const int lane = tid & 63;
    const int g = lane >> 4;     // quad 0..3
    const int c = lane & 15;     // col within tile

    const f32x4 zero4 = {0.f, 0.f, 0.f, 0.f};
    short* myPs = &PO[wid][0];

    for (int mt = wid; mt < 14; mt += 4) {
        int m0 = mt * 16;
        // A-frag: Q rows m0+c, cols g*8..+7, straight from global (bf16, 16B)
        s16x8 aq = {0, 0, 0, 0, 0, 0, 0, 0};
        int qtok = m0 + c;
        if (g < 3 && qtok < NTOK)
            aq = *(const s16x8*)(qw + hbase + (size_t)qtok * HD + g * 8);
        // S row-strip: 14 tiles (tile 13: clamped row, pad cols discarded below)
        f32x4 sreg[14];
#pragma unroll
        for (int t = 0; t < 14; t++) {
            int krow = (t < 13) ? (t * 16 + c) : (208 + (c & 7));
            const short* p = &Ks[krow * 36 + g * 8];
            s16x4 lo = *(const s16x4*)p;
            s16x4 hi = *(const s16x4*)(p + 4);
            s16x8 bk = __builtin_shufflevector(lo, hi, 0, 1, 2, 3, 4, 5, 6, 7);
            sreg[t] = __builtin_amdgcn_mfma_f32_16x16x32_bf16(aq, bk, zero4, 0, 0, 0);
        }
        // fused bias + mask + exp (fixed shift CEXP; softmax is shift-invariant)
        int gi[4], ei[4];
#pragma unroll
        for (int r = 0; r < 4; r++) {
            int eg = eg_s[m0 + g * 4 + r];
            ei[r] = eg & 1023;
            gi[r] = eg >> 10;
        }
        float sm[4] = {0.f, 0.f, 0.f, 0.f};
#pragma unroll
        for (int t = 0; t < 13; t++) {
            int j = t * 16 + c;
            int eg = eg_s[j];
            int ej = eg & 1023, gj = eg >> 10;
#pragma unroll
            for (int r = 0; r < 4; r++) {
                float s = sreg[t][r] + Lb[ei[r] - ej + 665];
                if (gi[r] != gj) s -= 100.f;
                float e = __expf(s - CEXP);
                sreg[t][r] = e;
                sm[r] += e;
            }
        }
        {   // tile 13: columns 208..223, c>=8 are pads -> force 0
            int j = 208 + c;
            int eg = eg_s[j];
            int ej = eg & 1023, gj = eg >> 10;
            bool padc = (c >= 8);
#pragma unroll
            for (int r = 0; r < 4; r++) {
                float s = sreg[13][r] + Lb[ei[r] - ej + 665];
                if (gi[r] != gj) s -= 100.f;
                float e = padc ? 0.f : __expf(s - CEXP);
                sreg[13][r] = e;
                sm[r] += e;
            }
        }
#pragma unroll
        for (int o = 1; o < 16; o <<= 1)
#pragma unroll
            for (int r = 0; r < 4; r++) sm[r] += __shfl_xor(sm[r], o);
        float rinv[4];
#pragma unroll
        for (int r = 0; r < 4; r++) rinv[r] = 1.f / sm[r];

        // PV: 7 k-chunks of 32, P staged via per-wave LDS (fully unrolled)
        f32x4 o0 = zero4, o1 = zero4;
#pragma unroll
        for (int kt = 0; kt < 7; kt++) {
#pragma unroll
            for (int tt = 0; tt < 2; tt++) {
                int t = kt * 2 + tt;
#pragma unroll
                for (int r = 0; r < 4; r++)
                    myPs[(g * 4 + r) * 36 + tt * 16 + c] = f2b(sreg[t][r]);
            }
            const short* p = &myPs[c * 36 + g * 8];
            s16x4 lo = *(const s16x4*)p;
            s16x4 hi = *(const s16x4*)(p + 4);
            s16x8 ap = __builtin_shufflevector(lo, hi, 0, 1, 2, 3, 4, 5, 6, 7);
            const short* pv0 = &Vt[c * VSTR + kt * 32 + g * 8];
            s16x4 v0l = *(const s16x4*)pv0;
            s16x4 v0h = *(const s16x4*)(pv0 + 4);
            s16x8 bv0 = __builtin_shufflevector(v0l, v0h, 0, 1, 2, 3, 4, 5, 6, 7);
            const short* pv1 = &Vt[(16 + c) * VSTR + kt * 32 + g * 8];
            s16x4 v1l = *(const s16x4*)pv1;
            s16x4 v1h = *(const s16x4*)(pv1 + 4);
            s16x8 bv1 = __builtin_shufflevector(v1l, v1h, 0, 1, 2, 3, 4, 5, 6, 7);
            o0 = __builtin_amdgcn_mfma_f32_16x16x32_bf16(ap, bv0, o0, 0, 0, 0);
            o1 = __builtin_amdgcn_mfma_f32_16x16x32_bf16(ap, bv1, o1, 0, 0, 0);
        }

        // epilogue: scale, stage bf16 O tile (reuses Ps), contiguous copy-out
#pragma unroll
        for (int r = 0; r < 4; r++) {
            int row = g * 4 + r;
            myPs[row * 24 + c] = f2b(o0[r] * rinv[r]);
            if (c < 8) myPs[row * 24 + 16 + c] = f2b(o1[r] * rinv[r]);
        }
        int nrow = NTOK - m0; if (nrow > 16) nrow = 16;
        int nsh = nrow * 24;                      // shorts (192 or 384)
        short* dstw = aw + hbase + (size_t)m0 * HD;
        for (int j = lane; j * 8 < nsh; j += 64)
            *(s16x8*)(dstw + j * 8) = *(const s16x8*)(myPs + j * 8);
    }
}

// ---- Kernel 3: output projection via f16 MFMA, swapped operands ----
// D[oc][vox]: A = Wp rows, B = X rows -> lane-c runs contiguous in vox,
// stores straight to out (64B coalesced), no restage.
__global__ __launch_bounds__(256) void out_proj_mfma_kernel(
    const short* __restrict__ aw, const float* __restrict__ Wp,
    const float* __restrict__ bp, const int* __restrict__ use_shift,
    float* __restrict__ out)
{
    __shared__ short Xs[128 * XSTR];   // f16 [vox][ch]
    __shared__ short Wb[CH * XSTR];    // f16 [oc][ic]

    int tid = threadIdx.x;
    int v0 = blockIdx.x * 128;

    for (int e = tid; e < CH * 48; e += 256) {
        int oc = e / 48, kp = e - oc * 48;
        float2 wv = *(const float2*)&Wp[oc * CH + 2 * kp];
        *(unsigned*)&Wb[oc * XSTR + 2 * kp] = pack_f16(wv.x, wv.y);
    }
    for (int e = tid; e < 512; e += 256) {
        int vox = e >> 2, hq = e & 3;
        int v = v0 + vox;
        int d = v / (DS * DS);
        int rem = v - d * DS * DS;
        int h = rem / DS;
        int w = rem - h * DS;
        int s = (use_shift[0] != 0) ? 3 : 0;
        int sd = d - s; if (sd < 0) sd += DS;
        int s_h = h - s; if (s_h < 0) s_h += DS;
        int s_w = w - s; if (s_w < 0) s_w += DS;
        int widx = (sd / WSZ) * 64 + (s_h / WSZ) * 8 + (s_w / WSZ);
        int tok  = (sd % WSZ) * 36 + (s_h % WSZ) * WSZ + (s_w % WSZ);
        const short* sp = aw + ((size_t)(widx * NHEADS + hq) * NTOK + tok) * HD;
#pragma unroll
        for (int j3 = 0; j3 < 3; j3++) {
            s16x8 a = *(const s16x8*)(sp + 8 * j3);
#pragma unroll
            for (int p = 0; p < 4; p++)
                *(unsigned*)&Xs[vox * XSTR + hq * 24 + 8 * j3 + 2 * p] =
                    pack_f16(bf2f(a[2 * p]), bf2f(a[2 * p + 1]));
        }
    }
    __syncthreads();

    const int wid = tid >> 6;
    const int lane = tid & 63;
    const int g = lane >> 4;
    const int c = lane & 15;

    const f32x4 zero4 = {0.f, 0.f, 0.f, 0.f};
    f32x4 acc[2][6];
#pragma unroll
    for (int i = 0; i < 2; i++)
#pragma unroll
        for (int j = 0; j < 6; j++) acc[i][j] = zero4;

#pragma unroll
    for (int kt = 0; kt < 3; kt++) {
        f16x8 bfr[2];
#pragma unroll
        for (int mi = 0; mi < 2; mi++) {
            const short* pb = &Xs[((2 * wid + mi) * 16 + c) * XSTR + kt * 32 + g * 8];
            s16x4 bl = *(const s16x4*)pb;
            s16x4 bh = *(const s16x4*)(pb + 4);
            bfr[mi] = __builtin_bit_cast(f16x8,
                __builtin_shufflevector(bl, bh, 0, 1, 2, 3, 4, 5, 6, 7));
        }
#pragma unroll
        for (int nt = 0; nt < 6; nt++) {
            const short* pa = &Wb[(nt * 16 + c) * XSTR + kt * 32 + g * 8];
            s16x4 al = *(const s16x4*)pa;
            s16x4 ah = *(const s16x4*)(pa + 4);
            f16x8 af = __builtin_bit_cast(f16x8,
                __builtin_shufflevector(al, ah, 0, 1, 2, 3, 4, 5, 6, 7));
            acc[0][nt] = __builtin_amdgcn_mfma_f32_16x16x32_f16(af, bfr[0], acc[0][nt], 0, 0, 0);
            acc[1][nt] = __builtin_amdgcn_mfma_f32_16x16x32_f16(af, bfr[1], acc[1][nt], 0, 0, 0);
        }
    }

#pragma unroll
    for (int nt = 0; nt < 6; nt++)
#pragma unroll
        for (int r = 0; r < 4; r++) {
            int oc = nt * 16 + g * 4 + r;
            float bb = bp[oc];
#pragma unroll
            for (int mi = 0; mi < 2; mi++) {
                int vox = v0 + (2 * wid + mi) * 16 + c;
                out[(size_t)oc * NVOX + vox] = acc[mi][nt][r] + bb;
            }
        }
}

extern "C" void kernel_launch(void* const* d_in, const int* in_sizes, int n_in,
                              void* d_out, int out_size, void* d_ws, size_t ws_size,
                              hipStream_t stream)
{
    const float* q_in = (const float*)d_in[0];
    const float* k_in = (const float*)d_in[1];
    const float* v_in = (const float*)d_in[2];
    const float* Wq   = (const float*)d_in[3];
    const float* bq   = (const float*)d_in[4];
    const float* Wk   = (const float*)d_in[5];
    const float* bk   = (const float*)d_in[6];
    const float* Wv   = (const float*)d_in[7];
    const float* bv   = (const float*)d_in[8];
    const float* Wp   = (const float*)d_in[9];
    const float* bp   = (const float*)d_in[10];
    const float* rel_table = (const float*)d_in[11];
    const int*   use_shift = (const int*)d_in[12];

    const size_t NELEM = (size_t)NWIN * NTOK * CH;   // 10,616,832
    short* qw = (short*)d_ws;                        // bf16
    short* kw = qw + NELEM;
    short* vw = kw + NELEM;
    short* aw = vw + NELEM;                          // bf16

    const float scale = 0.20412414523193154f;  // 1/sqrt(24)

    proj_mfma_kernel<<<3 * PGRID, 256, 0, stream>>>(
        q_in, k_in, v_in, Wq, Wk, Wv, bq, bk, bv, use_shift, qw, kw, vw, scale);
    attn_mfma_kernel<<<NWIN * NHEADS, 256, 0, stream>>>(qw, kw, vw, rel_table, use_shift, aw);
    out_proj_mfma_kernel<<<PGRID, 256, 0, stream>>>(aw, Wp, bp, use_shift, (float*)d_out);
}

// Round 7
// 278.985 us; speedup vs baseline: 2.0598x; 1.0904x over previous
//
#include <hip/hip_runtime.h>
#include <hip/hip_bf16.h>

// CrossWindowAttention3D — round 10: exp-domain bias table + MFMA row-sums.
// attn was latency-bound on per-element LDS gathers (eg_s->Lb) + mask VALU.
// (1) Precompute EB[head][wtype][224][224] = mask? 0 : exp(bias-8) (8 window
//     types = per-dim w==7 flags; pads=0). Inner loop: P = expf(s)*EB — no
//     gathers, no mask logic, no pad special-cases.
// (2) V channel 24 := 1.0 -> PV MFMA col 24 yields row sums; butterfly reduce
//     and sum-accumulate chain deleted; rinv via one shfl.
// LDS 40.5K -> 34.8K. proj / out_proj unchanged from round 9.
// ws: qw|kw|vw|aw (4 x 21.25 MB bf16) + EB (6.4 MB f32)

#define CH    96
#define DS    48
#define NVOX  (48*48*48)   // 110592
#define WSZ   6
#define NWIN  512
#define NTOK  216
#define NTOKP 224
#define NHEADS 4
#define HD    24
#define XSTR  100          // LDS row stride (shorts) for f16 GEMM tiles
#define VSTR  228          // Vt row stride (shorts)
#define PGRID (NVOX / 128) // 864 blocks per projection
#define CEXP  8.0f

typedef __attribute__((ext_vector_type(4))) float  f32x4;
typedef __attribute__((ext_vector_type(4))) short  s16x4;
typedef __attribute__((ext_vector_type(8))) short  s16x8;
typedef __attribute__((ext_vector_type(8))) _Float16 f16x8;

static __device__ inline short f2b(float f) {
    union { float f; unsigned u; } v; v.f = f;
    unsigned r = v.u + 0x7FFF + ((v.u >> 16) & 1);   // RTNE
    return (short)(r >> 16);
}
static __device__ inline float bf2f(short s) {
    union { unsigned u; float f; } v;
    v.u = ((unsigned)(unsigned short)s) << 16;
    return v.f;
}
static __device__ inline unsigned pack_f16(float a, float b) {
    unsigned short ua = __builtin_bit_cast(unsigned short, (_Float16)a);
    unsigned short ub = __builtin_bit_cast(unsigned short, (_Float16)b);
    return (unsigned)ua | ((unsigned)ub << 16);
}

// ---- Kernel 0: EB[head][type][224][224] = mask? 0 : exp(bias - CEXP) ----
// type bits: 1 = d-dim boundary window (wd==7), 2 = h-dim, 4 = w-dim.
__global__ __launch_bounds__(256) void eb_kernel(
    const float* __restrict__ rel_table, float* __restrict__ EB)
{
    int idx = blockIdx.x * 256 + threadIdx.x;     // 4*8*224*224, exact grid
    int head = idx / (8 * NTOKP * NTOKP);
    int rem = idx - head * 8 * NTOKP * NTOKP;
    int ty = rem / (NTOKP * NTOKP);
    int rem2 = rem - ty * NTOKP * NTOKP;
    int i = rem2 / NTOKP;
    int j = rem2 - (rem2 / NTOKP) * NTOKP;
    float val = 0.f;
    if (i < NTOK && j < NTOK) {
        int tdi = i / 36, thi = (i / 6) % 6, twi = i % 6;
        int tdj = j / 36, thj = (j / 6) % 6, twj = j % 6;
        bool m = ((ty & 1) && ((tdi < 3) != (tdj < 3))) ||
                 ((ty & 2) && ((thi < 3) != (thj < 3))) ||
                 ((ty & 4) && ((twi < 3) != (twj < 3)));
        int ridx = ((tdi - tdj + 5) * 11 + (thi - thj + 5)) * 11 + (twi - twj + 5);
        float b = rel_table[ridx * NHEADS + head];
        val = m ? 0.f : __expf(b - CEXP);
    }
    EB[idx] = val;
}

// ---- Kernel 1: conv1x1 + shift + window partition via f16 MFMA (round 8) ----
__global__ __launch_bounds__(256) void proj_mfma_kernel(
    const float* __restrict__ x0, const float* __restrict__ x1, const float* __restrict__ x2,
    const float* __restrict__ W0, const float* __restrict__ W1, const float* __restrict__ W2,
    const float* __restrict__ b0, const float* __restrict__ b1, const float* __restrict__ b2,
    const int* __restrict__ use_shift,
    short* __restrict__ d0, short* __restrict__ d1, short* __restrict__ d2,
    float scale0)
{
    __shared__ short Xs[128 * XSTR];   // f16 [vox][k]; later bf16 [vox][oc]
    __shared__ short Wb[CH * XSTR];    // f16 [oc][k]

    int tid = threadIdx.x;
    int which = blockIdx.x / PGRID;
    int bx = blockIdx.x - which * PGRID;
    int v0 = bx * 128;

    const float* x    = (which == 0) ? x0 : ((which == 1) ? x1 : x2);
    const float* W    = (which == 0) ? W0 : ((which == 1) ? W1 : W2);
    const float* bias = (which == 0) ? b0 : ((which == 1) ? b1 : b2);
    short*       dst  = (which == 0) ? d0 : ((which == 1) ? d1 : d2);
    float scale = (which == 0) ? scale0 : 1.0f;

    for (int e = tid; e < CH * 48; e += 256) {
        int oc = e / 48, kp = e - oc * 48;
        float2 wv = *(const float2*)&W[oc * CH + 2 * kp];
        *(unsigned*)&Wb[oc * XSTR + 2 * kp] = pack_f16(wv.x, wv.y);
    }
    {
        int vox = tid & 127;
        int v = v0 + vox;
        int d = v / (DS * DS);
        int rem = v - d * DS * DS;
        int h = rem / DS;
        int w = rem - h * DS;
        int s = (use_shift[0] != 0) ? 3 : 0;
        int sd = d + s; if (sd >= DS) sd -= DS;
        int s_h = h + s; if (s_h >= DS) s_h -= DS;
        int s_w = w + s; if (s_w >= DS) s_w -= DS;
        int src = (sd * DS + s_h) * DS + s_w;
        for (int e = tid; e < 128 * 48; e += 256) {
            int kp = e >> 7;
            float xa = x[(2 * kp) * NVOX + src];
            float xb = x[(2 * kp + 1) * NVOX + src];
            *(unsigned*)&Xs[vox * XSTR + 2 * kp] = pack_f16(xa, xb);
        }
    }
    __syncthreads();

    const int wid = tid >> 6;
    const int lane = tid & 63;
    const int g = lane >> 4;
    const int c = lane & 15;
    const int mrow = wid * 32;

    const f32x4 zero4 = {0.f, 0.f, 0.f, 0.f};
    f32x4 acc[2][6];
#pragma unroll
    for (int i = 0; i < 2; i++)
#pragma unroll
        for (int j = 0; j < 6; j++) acc[i][j] = zero4;

#pragma unroll
    for (int kt = 0; kt < 3; kt++) {
        const short* pa0 = &Xs[(mrow + c) * XSTR + kt * 32 + g * 8];
        s16x4 a0l = *(const s16x4*)pa0;
        s16x4 a0h = *(const s16x4*)(pa0 + 4);
        f16x8 a0 = __builtin_bit_cast(f16x8,
            __builtin_shufflevector(a0l, a0h, 0, 1, 2, 3, 4, 5, 6, 7));
        const short* pa1 = &Xs[(mrow + 16 + c) * XSTR + kt * 32 + g * 8];
        s16x4 a1l = *(const s16x4*)pa1;
        s16x4 a1h = *(const s16x4*)(pa1 + 4);
        f16x8 a1 = __builtin_bit_cast(f16x8,
            __builtin_shufflevector(a1l, a1h, 0, 1, 2, 3, 4, 5, 6, 7));
#pragma unroll
        for (int nt = 0; nt < 6; nt++) {
            const short* pb = &Wb[(nt * 16 + c) * XSTR + kt * 32 + g * 8];
            s16x4 bl = *(const s16x4*)pb;
            s16x4 bh = *(const s16x4*)(pb + 4);
            f16x8 bb = __builtin_bit_cast(f16x8,
                __builtin_shufflevector(bl, bh, 0, 1, 2, 3, 4, 5, 6, 7));
            acc[0][nt] = __builtin_amdgcn_mfma_f32_16x16x32_f16(a0, bb, acc[0][nt], 0, 0, 0);
            acc[1][nt] = __builtin_amdgcn_mfma_f32_16x16x32_f16(a1, bb, acc[1][nt], 0, 0, 0);
        }
    }

    float bs[6];
#pragma unroll
    for (int nt = 0; nt < 6; nt++) bs[nt] = bias[nt * 16 + c];

    __syncthreads();

#pragma unroll
    for (int mtile = 0; mtile < 2; mtile++)
#pragma unroll
        for (int nt = 0; nt < 6; nt++)
#pragma unroll
            for (int r = 0; r < 4; r++) {
                int vox = mrow + mtile * 16 + g * 4 + r;
                int oc = nt * 16 + c;
                Xs[vox * XSTR + oc] = f2b((acc[mtile][nt][r] + bs[nt]) * scale);
            }
    __syncthreads();

    for (int e = tid; e < 512; e += 256) {
        int vox = e >> 2, q = e & 3;
        int v = v0 + vox;
        int d = v / (DS * DS);
        int rem = v - d * DS * DS;
        int h = rem / DS;
        int w = rem - h * DS;
        int widx = (d / WSZ) * 64 + (h / WSZ) * 8 + (w / WSZ);
        int tok  = (d % WSZ) * 36 + (h % WSZ) * WSZ + (w % WSZ);
        short* dp = dst + ((size_t)(widx * NHEADS + q) * NTOK + tok) * HD;
        const short* sp = &Xs[vox * XSTR + q * 24];
        s16x4 a0 = *(const s16x4*)(sp);
        s16x4 a1 = *(const s16x4*)(sp + 4);
        s16x4 a2 = *(const s16x4*)(sp + 8);
        s16x4 a3 = *(const s16x4*)(sp + 12);
        s16x4 a4 = *(const s16x4*)(sp + 16);
        s16x4 a5 = *(const s16x4*)(sp + 20);
        *(s16x8*)(dp)      = __builtin_shufflevector(a0, a1, 0, 1, 2, 3, 4, 5, 6, 7);
        *(s16x8*)(dp + 8)  = __builtin_shufflevector(a2, a3, 0, 1, 2, 3, 4, 5, 6, 7);
        *(s16x8*)(dp + 16) = __builtin_shufflevector(a4, a5, 0, 1, 2, 3, 4, 5, 6, 7);
    }
}

// ---- Kernel 2: MFMA windowed attention. One block per (window, head). ----
// LDS: Ks[216*36] 15552 + Vt[32*228] 14592 + PO 4608 = 34752 B -> 4/CU.
__global__ __launch_bounds__(256) void attn_mfma_kernel(
    const short* __restrict__ qw, const short* __restrict__ kw,
    const short* __restrict__ vw, const float* __restrict__ EB,
    const int* __restrict__ use_shift, short* __restrict__ aw)
{
    __shared__ short Ks[NTOK * 36];
    __shared__ short Vt[32 * VSTR];
    __shared__ short PO[4][576];          // per-wave: Ps bf16[16][36] / Os bf16[16][24]

    int widx = blockIdx.x >> 2;
    int head = blockIdx.x & 3;
    int tid = threadIdx.x;
    bool shift = (use_shift[0] != 0);
    int wd = widx >> 6, wh = (widx >> 3) & 7, ww = widx & 7;
    int ty = shift ? ((wd == 7 ? 1 : 0) | (wh == 7 ? 2 : 0) | (ww == 7 ? 4 : 0)) : 0;

    // zero-init K pad slots + V rows; V channel 24 = 1.0 (row-sum trick)
    {
        int* z2 = (int*)Ks; int* z3 = (int*)Vt;
        for (int i = tid; i < NTOK * 18; i += 256) z2[i] = 0;
        for (int i = tid; i < 16 * VSTR; i += 256)
            z3[i] = (i >= 12 * VSTR && i < (25 * VSTR) / 2) ? 0x3F803F80 : 0;
        // ints [12*VSTR, 12.5*VSTR) == shorts [24*VSTR, 25*VSTR) == channel 24
    }
    __syncthreads();

    const size_t hbase = (size_t)(widx * NHEADS + head) * NTOK * HD;

    for (int e = tid; e < NTOK * 3; e += 256) {
        int t = e / 3, ch = e - t * 3;
        const short* kp = kw + hbase + t * 24 + ch * 8;
        s16x8 k8 = *(const s16x8*)kp;
        *(s16x4*)&Ks[t * 36 + ch * 8]     = __builtin_shufflevector(k8, k8, 0, 1, 2, 3);
        *(s16x4*)&Ks[t * 36 + ch * 8 + 4] = __builtin_shufflevector(k8, k8, 4, 5, 6, 7);
        s16x8 v8 = *(const s16x8*)(vw + hbase + t * 24 + ch * 8);
#pragma unroll
        for (int j = 0; j < 8; j++) Vt[(ch * 8 + j) * VSTR + t] = v8[j];
    }
    __syncthreads();

    const int wid = tid >> 6;
    const int lane = tid & 63;
    const int g = lane >> 4;     // quad 0..3
    const int c = lane & 15;     // col within tile

    const f32x4 zero4 = {0.f, 0.f, 0.f, 0.f};
    short* myPs = &PO[wid][0];
    const float* EBt = EB + (size_t)(head * 8 + ty) * NTOKP * NTOKP;

    for (int mt = wid; mt < 14; mt += 4) {
        int m0 = mt * 16;
        // A-frag: Q rows m0+c, cols g*8..+7, straight from global (bf16, 16B)
        s16x8 aq = {0, 0, 0, 0, 0, 0, 0, 0};
        int qtok = m0 + c;
        if (g < 3 && qtok < NTOK)
            aq = *(const s16x8*)(qw + hbase + (size_t)qtok * HD + g * 8);
        // S row-strip: 14 tiles (tile 13: clamped row; pads killed by EB=0)
        f32x4 sreg[14];
#pragma unroll
        for (int t = 0; t < 14; t++) {
            int krow = (t < 13) ? (t * 16 + c) : (208 + (c & 7));
            const short* p = &Ks[krow * 36 + g * 8];
            s16x4 lo = *(const s16x4*)p;
            s16x4 hi = *(const s16x4*)(p + 4);
            s16x8 bk = __builtin_shufflevector(lo, hi, 0, 1, 2, 3, 4, 5, 6, 7);
            sreg[t] = __builtin_amdgcn_mfma_f32_16x16x32_bf16(aq, bk, zero4, 0, 0, 0);
        }
        // P = exp(s) * EB[i][j]  (bias/mask/pad all folded into EB)
        const float* ebr[4];
#pragma unroll
        for (int r = 0; r < 4; r++)
            ebr[r] = EBt + (size_t)(m0 + g * 4 + r) * NTOKP + c;
#pragma unroll
        for (int t = 0; t < 14; t++)
#pragma unroll
            for (int r = 0; r < 4; r++)
                sreg[t][r] = __expf(sreg[t][r]) * ebr[r][t * 16];

        // PV: 7 k-chunks of 32, P staged via per-wave LDS (fully unrolled)
        f32x4 o0 = zero4, o1 = zero4;
#pragma unroll
        for (int kt = 0; kt < 7; kt++) {
#pragma unroll
            for (int tt = 0; tt < 2; tt++) {
                int t = kt * 2 + tt;
#pragma unroll
                for (int r = 0; r < 4; r++)
                    myPs[(g * 4 + r) * 36 + tt * 16 + c] = f2b(sreg[t][r]);
            }
            const short* p = &myPs[c * 36 + g * 8];
            s16x4 lo = *(const s16x4*)p;
            s16x4 hi = *(const s16x4*)(p + 4);
            s16x8 ap = __builtin_shufflevector(lo, hi, 0, 1, 2, 3, 4, 5, 6, 7);
            const short* pv0 = &Vt[c * VSTR + kt * 32 + g * 8];
            s16x4 v0l = *(const s16x4*)pv0;
            s16x4 v0h = *(const s16x4*)(pv0 + 4);
            s16x8 bv0 = __builtin_shufflevector(v0l, v0h, 0, 1, 2, 3, 4, 5, 6, 7);
            const short* pv1 = &Vt[(16 + c) * VSTR + kt * 32 + g * 8];
            s16x4 v1l = *(const s16x4*)pv1;
            s16x4 v1h = *(const s16x4*)(pv1 + 4);
            s16x8 bv1 = __builtin_shufflevector(v1l, v1h, 0, 1, 2, 3, 4, 5, 6, 7);
            o0 = __builtin_amdgcn_mfma_f32_16x16x32_bf16(ap, bv0, o0, 0, 0, 0);
            o1 = __builtin_amdgcn_mfma_f32_16x16x32_bf16(ap, bv1, o1, 0, 0, 0);
        }

        // row sums live in o1 col 24 (V ones-channel) = lane c==8 of each quad
#pragma unroll
        for (int r = 0; r < 4; r++) {
            float sm = __shfl(o1[r], (lane & 48) + 8);
            float ri = 1.f / sm;
            int row = g * 4 + r;
            myPs[row * 24 + c] = f2b(o0[r] * ri);
            if (c < 8) myPs[row * 24 + 16 + c] = f2b(o1[r] * ri);
        }
        int nrow = NTOK - m0; if (nrow > 16) nrow = 16;
        int nsh = nrow * 24;                      // shorts (192 or 384)
        short* dstw = aw + hbase + (size_t)m0 * HD;
        for (int j = lane; j * 8 < nsh; j += 64)
            *(s16x8*)(dstw + j * 8) = *(const s16x8*)(myPs + j * 8);
    }
}

// ---- Kernel 3: output projection via f16 MFMA, swapped operands ----
__global__ __launch_bounds__(256) void out_proj_mfma_kernel(
    const short* __restrict__ aw, const float* __restrict__ Wp,
    const float* __restrict__ bp, const int* __restrict__ use_shift,
    float* __restrict__ out)
{
    __shared__ short Xs[128 * XSTR];   // f16 [vox][ch]
    __shared__ short Wb[CH * XSTR];    // f16 [oc][ic]

    int tid = threadIdx.x;
    int v0 = blockIdx.x * 128;

    for (int e = tid; e < CH * 48; e += 256) {
        int oc = e / 48, kp = e - oc * 48;
        float2 wv = *(const float2*)&Wp[oc * CH + 2 * kp];
        *(unsigned*)&Wb[oc * XSTR + 2 * kp] = pack_f16(wv.x, wv.y);
    }
    for (int e = tid; e < 512; e += 256) {
        int vox = e >> 2, hq = e & 3;
        int v = v0 + vox;
        int d = v / (DS * DS);
        int rem = v - d * DS * DS;
        int h = rem / DS;
        int w = rem - h * DS;
        int s = (use_shift[0] != 0) ? 3 : 0;
        int sd = d - s; if (sd < 0) sd += DS;
        int s_h = h - s; if (s_h < 0) s_h += DS;
        int s_w = w - s; if (s_w < 0) s_w += DS;
        int widx = (sd / WSZ) * 64 + (s_h / WSZ) * 8 + (s_w / WSZ);
        int tok  = (sd % WSZ) * 36 + (s_h % WSZ) * WSZ + (s_w % WSZ);
        const short* sp = aw + ((size_t)(widx * NHEADS + hq) * NTOK + tok) * HD;
#pragma unroll
        for (int j3 = 0; j3 < 3; j3++) {
            s16x8 a = *(const s16x8*)(sp + 8 * j3);
#pragma unroll
            for (int p = 0; p < 4; p++)
                *(unsigned*)&Xs[vox * XSTR + hq * 24 + 8 * j3 + 2 * p] =
                    pack_f16(bf2f(a[2 * p]), bf2f(a[2 * p + 1]));
        }
    }
    __syncthreads();

    const int wid = tid >> 6;
    const int lane = tid & 63;
    const int g = lane >> 4;
    const int c = lane & 15;

    const f32x4 zero4 = {0.f, 0.f, 0.f, 0.f};
    f32x4 acc[2][6];
#pragma unroll
    for (int i = 0; i < 2; i++)
#pragma unroll
        for (int j = 0; j < 6; j++) acc[i][j] = zero4;

#pragma unroll
    for (int kt = 0; kt < 3; kt++) {
        f16x8 bfr[2];
#pragma unroll
        for (int mi = 0; mi < 2; mi++) {
            const short* pb = &Xs[((2 * wid + mi) * 16 + c) * XSTR + kt * 32 + g * 8];
            s16x4 bl = *(const s16x4*)pb;
            s16x4 bh = *(const s16x4*)(pb + 4);
            bfr[mi] = __builtin_bit_cast(f16x8,
                __builtin_shufflevector(bl, bh, 0, 1, 2, 3, 4, 5, 6, 7));
        }
#pragma unroll
        for (int nt = 0; nt < 6; nt++) {
            const short* pa = &Wb[(nt * 16 + c) * XSTR + kt * 32 + g * 8];
            s16x4 al = *(const s16x4*)pa;
            s16x4 ah = *(const s16x4*)(pa + 4);
            f16x8 af = __builtin_bit_cast(f16x8,
                __builtin_shufflevector(al, ah, 0, 1, 2, 3, 4, 5, 6, 7));
            acc[0][nt] = __builtin_amdgcn_mfma_f32_16x16x32_f16(af, bfr[0], acc[0][nt], 0, 0, 0);
            acc[1][nt] = __builtin_amdgcn_mfma_f32_16x16x32_f16(af, bfr[1], acc[1][nt], 0, 0, 0);
        }
    }

#pragma unroll
    for (int nt = 0; nt < 6; nt++)
#pragma unroll
        for (int r = 0; r < 4; r++) {
            int oc = nt * 16 + g * 4 + r;
            float bb = bp[oc];
#pragma unroll
            for (int mi = 0; mi < 2; mi++) {
                int vox = v0 + (2 * wid + mi) * 16 + c;
                out[(size_t)oc * NVOX + vox] = acc[mi][nt][r] + bb;
            }
        }
}

extern "C" void kernel_launch(void* const* d_in, const int* in_sizes, int n_in,
                              void* d_out, int out_size, void* d_ws, size_t ws_size,
                              hipStream_t stream)
{
    const float* q_in = (const float*)d_in[0];
    const float* k_in = (const float*)d_in[1];
    const float* v_in = (const float*)d_in[2];
    const float* Wq   = (const float*)d_in[3];
    const float* bq   = (const float*)d_in[4];
    const float* Wk   = (const float*)d_in[5];
    const float* bk   = (const float*)d_in[6];
    const float* Wv   = (const float*)d_in[7];
    const float* bv   = (const float*)d_in[8];
    const float* Wp   = (const float*)d_in[9];
    const float* bp   = (const float*)d_in[10];
    const float* rel_table = (const float*)d_in[11];
    const int*   use_shift = (const int*)d_in[12];

    const size_t NELEM = (size_t)NWIN * NTOK * CH;   // 10,616,832
    short* qw = (short*)d_ws;                        // bf16
    short* kw = qw + NELEM;
    short* vw = kw + NELEM;
    short* aw = vw + NELEM;                          // bf16
    float* EB = (float*)(aw + NELEM);                // 4*8*224*224 f32, 6.4MB

    const float scale = 0.20412414523193154f;  // 1/sqrt(24)

    eb_kernel<<<NHEADS * 8 * NTOKP * NTOKP / 256, 256, 0, stream>>>(rel_table, EB);
    proj_mfma_kernel<<<3 * PGRID, 256, 0, stream>>>(
        q_in, k_in, v_in, Wq, Wk, Wv, bq, bk, bv, use_shift, qw, kw, vw, scale);
    attn_mfma_kernel<<<NWIN * NHEADS, 256, 0, stream>>>(qw, kw, vw, EB, use_shift, aw);
    out_proj_mfma_kernel<<<PGRID, 256, 0, stream>>>(aw, Wp, bp, use_shift, (float*)d_out);
}